// Round 12
// baseline (291.800 us; speedup 1.0000x reference)
//
#include <hip/hip_runtime.h>
#include <hip/hip_bf16.h>
#include <stdint.h>

#define DIN 2048
#define DEMB 1024
#define NSUP 2048
#define NQRY 16384
#define NWAY 64

typedef __attribute__((ext_vector_type(8))) short bf16x8;
typedef __attribute__((ext_vector_type(4))) float f32x4;

__device__ inline unsigned short f2bf(float f) {
    union { float f; uint32_t u; } v; v.f = f;
    uint32_t u = v.u;
    uint32_t r = (u + 0x7FFFu + ((u >> 16) & 1u)) >> 16;
    return (unsigned short)r;
}

#define GLL(g, l) __builtin_amdgcn_global_load_lds(                                   \
    (const __attribute__((address_space(1))) void*)(g),                               \
    (__attribute__((address_space(3))) void*)(l), 16, 0, 0)

// ---------------- conversion kernels ----------------

__global__ void cvt_f32_bf16(const float* __restrict__ in, unsigned short* __restrict__ out, int n) {
    int i = (blockIdx.x * blockDim.x + threadIdx.x) * 4;
    int stride = gridDim.x * blockDim.x * 4;
    for (; i < n; i += stride) {
        float4 v = *(const float4*)(in + i);
        ushort4 o;
        o.x = f2bf(v.x); o.y = f2bf(v.y); o.z = f2bf(v.z); o.w = f2bf(v.w);
        *(ushort4*)(out + i) = o;
    }
}

// W [DIN][DEMB] f32  ->  Wt [DEMB][DIN] bf16
__global__ void cvt_transpose(const float* __restrict__ W, unsigned short* __restrict__ Wt) {
    __shared__ float tile[32][33];
    int c0 = blockIdx.x * 32;
    int r0 = blockIdx.y * 32;
    int tc = threadIdx.x & 31, tr = threadIdx.x >> 5;
    #pragma unroll
    for (int i = 0; i < 4; i++)
        tile[tr + 8*i][tc] = W[(size_t)(r0 + tr + 8*i) * DEMB + c0 + tc];
    __syncthreads();
    #pragma unroll
    for (int i = 0; i < 4; i++)
        Wt[(size_t)(c0 + tr + 8*i) * DIN + r0 + tc] = f2bf(tile[tc][tr + 8*i]);
}

// ---------------- query GEMM: BM=256, BN=256, BK=64, 512 thr, 2-buf counted-vmcnt ------
// 8 waves (2M x 4N), per-wave output 128x64 = acc[8][4]; 64 MFMA per wave per K-tile.
// LDS: 2 bufs x (A 32KB + B 32KB) = 128KB -> 1 block/CU, grid 256 = 1/CU.
// Layout per buf: [8 kg][256 row][8] kgrp-major (conflict-free, measured 0 conflicts).
// Staging: 8 x global_load_lds(16B)/thread/K-tile; steady s_waitcnt vmcnt(8) keeps the
// next tile's loads in flight across the barrier (r9-verified discipline).
// T5: s_setprio(1) around the MFMA cluster (per-wave vmcnt destaggers waves).
__global__ __launch_bounds__(512) void gemm256_query(
    const unsigned short* __restrict__ A,
    const unsigned short* __restrict__ Bt,
    const float* __restrict__ bias,
    unsigned short* __restrict__ emb_out,
    float* __restrict__ qsq)
{
    __shared__ __attribute__((aligned(16))) unsigned short AsF[2 * 16384];
    __shared__ __attribute__((aligned(16))) unsigned short BsF[2 * 16384];

    const int tid = threadIdx.x;
    const int nblk = DEMB / 256;          // 4
    // XCD-panel grouping (verified r8). gridDim.x = 256, %8 == 0.
    const int h = blockIdx.x;
    const int cpx = (int)(gridDim.x >> 3);
    const int wg = (h & 7) * cpx + (h >> 3);
    const int bx = wg % nblk, by = wg / nblk;
    const int brow = by * 256, bcol = bx * 256;
    const int lane = tid & 63, wid = tid >> 6;
    const int wr = wid >> 2, wc = wid & 3;          // 2M x 4N

    // staging: thread -> row (tid&255), k-group base (tid>>8); p=0..3 adds kg+2p.
    // LDS slot s = p*512 + tid -> elem off p*4096 + tid*8 == [kg=2p+(tid>>8)][row=tid&255].
    const int rows = tid & 255, kg0 = tid >> 8;
    const unsigned short* ga = A  + (size_t)(brow + rows) * DIN + kg0 * 8;
    const unsigned short* gb = Bt + (size_t)(bcol + rows) * DIN + kg0 * 8;

    f32x4 acc[8][4];
    #pragma unroll
    for (int i = 0; i < 8; i++)
        #pragma unroll
        for (int j = 0; j < 4; j++) acc[i][j] = (f32x4)(0.f);

    auto stageAB = [&](int buf) {
        unsigned short* la = AsF + buf * 16384 + tid * 8;
        unsigned short* lb = BsF + buf * 16384 + tid * 8;
        #pragma unroll
        for (int p = 0; p < 4; p++) {
            GLL(ga + p * 16, la + p * 4096);
            GLL(gb + p * 16, lb + p * 4096);
        }
        ga += 64; gb += 64;
    };

    stageAB(0);   // prologue

    const int kgl = lane >> 4, r = lane & 15;
    const int NT = DIN / 64;   // 32
    for (int t = 0; t < NT; ++t) {
        const int cur = t & 1;
        if (t < NT - 1) {
            stageAB(cur ^ 1);                                  // in flight across barrier
            asm volatile("s_waitcnt vmcnt(8)" ::: "memory");   // only stage(t) must land
        } else {
            asm volatile("s_waitcnt vmcnt(0)" ::: "memory");
        }
        __builtin_amdgcn_s_barrier();
        asm volatile("" ::: "memory");

        const unsigned short* Ab = AsF + cur * 16384;
        const unsigned short* Bb = BsF + cur * 16384;
        __builtin_amdgcn_s_setprio(1);
        #pragma unroll
        for (int ks = 0; ks < 2; ks++) {
            bf16x8 bfm[4], af[8];
            #pragma unroll
            for (int ni = 0; ni < 4; ni++)
                bfm[ni] = *(const bf16x8*)&Bb[((ks * 4 + kgl) * 256 + wc * 64 + ni * 16 + r) * 8];
            #pragma unroll
            for (int mi = 0; mi < 8; mi++)
                af[mi] = *(const bf16x8*)&Ab[((ks * 4 + kgl) * 256 + wr * 128 + mi * 16 + r) * 8];
            #pragma unroll
            for (int mi = 0; mi < 8; mi++)
                #pragma unroll
                for (int ni = 0; ni < 4; ni++)
                    acc[mi][ni] = __builtin_amdgcn_mfma_f32_16x16x32_bf16(af[mi], bfm[ni], acc[mi][ni], 0, 0, 0);
        }
        __builtin_amdgcn_s_setprio(0);
        asm volatile("" ::: "memory");
        __builtin_amdgcn_s_barrier();   // all waves done reading buf cur
    }

    const int r16 = lane & 15, quad = lane >> 4;
    float bv[4];
    #pragma unroll
    for (int ni = 0; ni < 4; ni++) bv[ni] = bias[bcol + wc * 64 + ni * 16 + r16];

    #pragma unroll
    for (int mi = 0; mi < 8; mi++) {
        float s0 = 0.f, s1 = 0.f, s2 = 0.f, s3 = 0.f;
        #pragma unroll
        for (int j = 0; j < 4; j++) {
            int row = brow + wr * 128 + mi * 16 + quad * 4 + j;
            float sj = 0.f;
            #pragma unroll
            for (int ni = 0; ni < 4; ni++) {
                float e = acc[mi][ni][j] + bv[ni];
                emb_out[(size_t)row * DEMB + bcol + wc * 64 + ni * 16 + r16] = f2bf(e);
                sj += e * e;
            }
            if (j == 0) s0 = sj; else if (j == 1) s1 = sj; else if (j == 2) s2 = sj; else s3 = sj;
        }
        float sv[4] = { s0, s1, s2, s3 };
        #pragma unroll
        for (int j = 0; j < 4; j++) {
            float v = sv[j];
            v += __shfl_xor(v, 1);
            v += __shfl_xor(v, 2);
            v += __shfl_xor(v, 4);
            v += __shfl_xor(v, 8);
            if (r16 == 0) {
                int row = brow + wr * 128 + mi * 16 + quad * 4 + j;
                atomicAdd(&qsq[row], v);
            }
        }
    }
}

// ---------------- support GEMM: r11-verified BM=128/BN=128 2-buf counted-vmcnt ---------
__global__ __launch_bounds__(256, 2) void gemm_support(
    const unsigned short* __restrict__ A,
    const unsigned short* __restrict__ Bt,
    const float* __restrict__ bias,
    const int* __restrict__ labels,
    float* __restrict__ proto_sums)
{
    constexpr int ASZ = 4 * 128 * 8;
    __shared__ __attribute__((aligned(16))) unsigned short AsF[2 * ASZ];
    __shared__ __attribute__((aligned(16))) unsigned short BsF[2 * ASZ];

    const int tid = threadIdx.x;
    const int nblk = DEMB / 128;          // 8
    const int h = blockIdx.x;
    const int cpx = (int)(gridDim.x >> 3);
    const int wg = (h & 7) * cpx + (h >> 3);
    const int bx = wg % nblk, by = wg / nblk;
    const int brow = by * 128, bcol = bx * 128;
    const int lane = tid & 63, wid = tid >> 6;
    const int wr = wid >> 1, wc = wid & 1;

    const int rowa = tid & 127, kga = tid >> 7;
    const unsigned short* ga = A  + (size_t)(brow + rowa) * DIN + kga * 8;
    const unsigned short* gb = Bt + (size_t)(bcol + rowa) * DIN + kga * 8;

    f32x4 acc[4][4];
    #pragma unroll
    for (int i = 0; i < 4; i++)
        #pragma unroll
        for (int j = 0; j < 4; j++) acc[i][j] = (f32x4)(0.f);

    auto stageAB = [&](int buf) {
        unsigned short* la = AsF + buf * ASZ + tid * 8;
        unsigned short* lb = BsF + buf * ASZ + tid * 8;
        GLL(ga, la); GLL(ga + 16, la + 2048);
        GLL(gb, lb); GLL(gb + 16, lb + 2048);
        ga += 32; gb += 32;
    };

    stageAB(0);

    const int kg = lane >> 4, r = lane & 15;
    const int NT = DIN / 32;   // 64
    for (int t = 0; t < NT; ++t) {
        const int cur = t & 1;
        if (t < NT - 1) {
            stageAB(cur ^ 1);
            asm volatile("s_waitcnt vmcnt(4)" ::: "memory");
        } else {
            asm volatile("s_waitcnt vmcnt(0)" ::: "memory");
        }
        __builtin_amdgcn_s_barrier();
        asm volatile("" ::: "memory");

        const unsigned short* Ab = AsF + cur * ASZ;
        const unsigned short* Bb = BsF + cur * ASZ;
        bf16x8 af[4], bfm[4];
        #pragma unroll
        for (int mi = 0; mi < 4; mi++)
            af[mi] = *(const bf16x8*)&Ab[(kg * 128 + wr * 64 + mi * 16 + r) * 8];
        #pragma unroll
        for (int ni = 0; ni < 4; ni++)
            bfm[ni] = *(const bf16x8*)&Bb[(kg * 128 + wc * 64 + ni * 16 + r) * 8];
        #pragma unroll
        for (int mi = 0; mi < 4; mi++)
            #pragma unroll
            for (int ni = 0; ni < 4; ni++)
                acc[mi][ni] = __builtin_amdgcn_mfma_f32_16x16x32_bf16(af[mi], bfm[ni], acc[mi][ni], 0, 0, 0);

        asm volatile("" ::: "memory");
        __builtin_amdgcn_s_barrier();
    }

    const int r16 = lane & 15, quad = lane >> 4;
    float bv[4];
    #pragma unroll
    for (int ni = 0; ni < 4; ni++) bv[ni] = bias[bcol + wc * 64 + ni * 16 + r16];

    #pragma unroll
    for (int mi = 0; mi < 4; mi++) {
        #pragma unroll
        for (int j = 0; j < 4; j++) {
            int row = brow + wr * 64 + mi * 16 + quad * 4 + j;
            int lab = labels[row];
            #pragma unroll
            for (int ni = 0; ni < 4; ni++) {
                float e = acc[mi][ni][j] + bv[ni];
                atomicAdd(&proto_sums[(size_t)lab * DEMB + bcol + wc * 64 + ni * 16 + r16], e);
            }
        }
    }
}

// ---------------- prototype normalize ----------------
__global__ void proto_norm(const float* __restrict__ proto_sums,
                           const int* __restrict__ labels,
                           unsigned short* __restrict__ proto_bf16,
                           float* __restrict__ psq) {
    int c = blockIdx.x;
    int tid = threadIdx.x;
    int cnt = 0;
    for (int i = tid; i < NSUP; i += 256) cnt += (labels[i] == c) ? 1 : 0;
    #pragma unroll
    for (int m = 1; m < 64; m <<= 1) cnt += __shfl_xor(cnt, m);
    __shared__ int warp_cnt[4];
    __shared__ float warp_ss[4];
    if ((tid & 63) == 0) warp_cnt[tid >> 6] = cnt;
    __syncthreads();
    int total = warp_cnt[0] + warp_cnt[1] + warp_cnt[2] + warp_cnt[3];
    float inv = 1.0f / (float)total;
    float ss = 0.f;
    for (int j = tid; j < DEMB; j += 256) {
        float p = proto_sums[(size_t)c * DEMB + j] * inv;
        proto_bf16[(size_t)c * DEMB + j] = f2bf(p);
        ss += p * p;
    }
    #pragma unroll
    for (int m = 1; m < 64; m <<= 1) ss += __shfl_xor(ss, m);
    if ((tid & 63) == 0) warp_ss[tid >> 6] = ss;
    __syncthreads();
    if (tid == 0) psq[c] = warp_ss[0] + warp_ss[1] + warp_ss[2] + warp_ss[3];
}

// ---------------- scores: out[q][c] = -sqrt(max(qsq+psq-2*dot,0)) ----------------
__global__ __launch_bounds__(256) void scores_kernel(
    const unsigned short* __restrict__ q_emb,
    const unsigned short* __restrict__ protos,
    const float* __restrict__ qsq, const float* __restrict__ psq,
    float* __restrict__ out)
{
    int tid = threadIdx.x, lane = tid & 63, wid = tid >> 6;
    int q0 = blockIdx.x * 64 + wid * 16;
    int r = lane & 15, quad = lane >> 4;
    f32x4 acc[4];
    #pragma unroll
    for (int i = 0; i < 4; i++) acc[i] = (f32x4)(0.f);
    const unsigned short* arow = q_emb + (size_t)(q0 + r) * DEMB + quad * 8;
    for (int k0 = 0; k0 < DEMB; k0 += 32) {
        bf16x8 a = *(const bf16x8*)(arow + k0);
        #pragma unroll
        for (int ni = 0; ni < 4; ni++) {
            bf16x8 bfrag = *(const bf16x8*)(protos + (size_t)(ni * 16 + r) * DEMB + k0 + quad * 8);
            acc[ni] = __builtin_amdgcn_mfma_f32_16x16x32_bf16(a, bfrag, acc[ni], 0, 0, 0);
        }
    }
    #pragma unroll
    for (int ni = 0; ni < 4; ni++) {
        int c = ni * 16 + r;
        float ps = psq[c];
        #pragma unroll
        for (int j = 0; j < 4; j++) {
            int row = q0 + quad * 4 + j;
            float d2 = qsq[row] + ps - 2.0f * acc[ni][j];
            d2 = fmaxf(d2, 0.0f);
            out[(size_t)row * NWAY + c] = -sqrtf(d2);
        }
    }
}

// ---------------- launch ----------------
extern "C" void kernel_launch(void* const* d_in, const int* in_sizes, int n_in,
                              void* d_out, int out_size, void* d_ws, size_t ws_size,
                              hipStream_t stream) {
    const float* support = (const float*)d_in[0];
    const float* query   = (const float*)d_in[1];
    const int*   labels  = (const int*)d_in[2];
    // d_in[3] = n_way (assumed 64)
    const float* W       = (const float*)d_in[4];
    const float* bias    = (const float*)d_in[5];
    float* out = (float*)d_out;

    char* ws = (char*)d_ws;
    unsigned short* q_bf     = (unsigned short*)(ws);                 // 67108864 B
    unsigned short* s_bf     = (unsigned short*)(ws + 67108864);      //  8388608 B
    unsigned short* Wt       = (unsigned short*)(ws + 75497472);      //  4194304 B
    unsigned short* q_emb    = (unsigned short*)(ws + 79691776);      // 33554432 B
    float*          proto_sums = (float*)(ws + 113246208);            //   262144 B
    unsigned short* proto_bf = (unsigned short*)(ws + 113508352);     //   131072 B
    float*          qsq      = (float*)(ws + 113639424);              //    65536 B
    float*          psq      = (float*)(ws + 113704960);              //      256 B

    hipMemsetAsync(proto_sums, 0, (size_t)NWAY * DEMB * sizeof(float), stream);
    hipMemsetAsync(qsq, 0, (size_t)NQRY * sizeof(float), stream);

    cvt_f32_bf16<<<2048, 256, 0, stream>>>(query, q_bf, NQRY * DIN);
    cvt_f32_bf16<<<512, 256, 0, stream>>>(support, s_bf, NSUP * DIN);
    dim3 tg(DEMB / 32, DIN / 32);
    cvt_transpose<<<tg, 256, 0, stream>>>(W, Wt);

    gemm_support<<<(NSUP / 128) * (DEMB / 128), 256, 0, stream>>>(
        s_bf, Wt, bias, labels, proto_sums);
    proto_norm<<<NWAY, 256, 0, stream>>>(proto_sums, labels, proto_bf, psq);
    gemm256_query<<<(NQRY / 256) * (DEMB / 256), 512, 0, stream>>>(
        q_bf, Wt, bias, q_emb, qsq);
    scores_kernel<<<NQRY / 64, 256, 0, stream>>>(q_emb, proto_bf, qsq, psq, out);
}

// Round 14
// 256.492 us; speedup vs baseline: 1.1377x; 1.1377x over previous
//
#include <hip/hip_runtime.h>
#include <hip/hip_bf16.h>
#include <stdint.h>

#define DIN 2048
#define DEMB 1024
#define NSUP 2048
#define NQRY 16384
#define NWAY 64

typedef __attribute__((ext_vector_type(8))) short bf16x8;
typedef __attribute__((ext_vector_type(4))) float f32x4;

__device__ inline unsigned short f2bf(float f) {
    union { float f; uint32_t u; } v; v.f = f;
    uint32_t u = v.u;
    uint32_t r = (u + 0x7FFFu + ((u >> 16) & 1u)) >> 16;
    return (unsigned short)r;
}

#define GLL(g, l) __builtin_amdgcn_global_load_lds(                                   \
    (const __attribute__((address_space(1))) void*)(g),                               \
    (__attribute__((address_space(3))) void*)(l), 16, 0, 0)

// ---------------- conversion kernels ----------------

__global__ void cvt_f32_bf16(const float* __restrict__ in, unsigned short* __restrict__ out, int n) {
    int i = (blockIdx.x * blockDim.x + threadIdx.x) * 4;
    int stride = gridDim.x * blockDim.x * 4;
    for (; i < n; i += stride) {
        float4 v = *(const float4*)(in + i);
        ushort4 o;
        o.x = f2bf(v.x); o.y = f2bf(v.y); o.z = f2bf(v.z); o.w = f2bf(v.w);
        *(ushort4*)(out + i) = o;
    }
}

// W [DIN][DEMB] f32  ->  Wt [DEMB][DIN] bf16
__global__ void cvt_transpose(const float* __restrict__ W, unsigned short* __restrict__ Wt) {
    __shared__ float tile[32][33];
    int c0 = blockIdx.x * 32;
    int r0 = blockIdx.y * 32;
    int tc = threadIdx.x & 31, tr = threadIdx.x >> 5;
    #pragma unroll
    for (int i = 0; i < 4; i++)
        tile[tr + 8*i][tc] = W[(size_t)(r0 + tr + 8*i) * DEMB + c0 + tc];
    __syncthreads();
    #pragma unroll
    for (int i = 0; i < 4; i++)
        Wt[(size_t)(c0 + tr + 8*i) * DIN + r0 + tc] = f2bf(tile[tc][tr + 8*i]);
}

// ---------------- query GEMM: r11 shape (BM=128, BN=256, BK=32, 2-buf counted-vmcnt)
// + FUSED A-convert: A read as f32, reg-staged (dwordx4 -> f2bf RNE -> ds_write_b128).
// Loads for tile t+1 issued at iter t (1-iter lookahead); vmcnt(0) at loop top confirms
// A-regs(t) + B-GLL(t); lgkmcnt(0) before barrier makes ds_writes cross-wave visible.
// Buffer audit: every write targets a buffer freed by the prev iter's trailing barrier.
__global__ __launch_bounds__(256, 2) void gemm_query(
    const float* __restrict__ A,              // f32 [NQRY][DIN]
    const unsigned short* __restrict__ Bt,    // bf16 [DEMB][DIN]
    const float* __restrict__ bias,
    unsigned short* __restrict__ emb_out,
    float* __restrict__ qsq)
{
    constexpr int ASZ = 4 * 128 * 8;          // 4096 elems/buf (8 KB)
    constexpr int BSZ = 4 * 256 * 8;          // 8192 elems/buf (16 KB)
    __shared__ __attribute__((aligned(16))) unsigned short AsF[2 * ASZ];
    __shared__ __attribute__((aligned(16))) unsigned short BsF[2 * BSZ];

    const int tid = threadIdx.x;
    const int nblk = DEMB / 256;              // 4
    // XCD-panel grouping (verified r8). gridDim.x = 512, %8 == 0.
    const int h = blockIdx.x;
    const int cpx = (int)(gridDim.x >> 3);
    const int wg = (h & 7) * cpx + (h >> 3);
    const int bx = wg % nblk, by = wg / nblk;
    const int brow = by * 128, bcol = bx * 256;
    const int lane = tid & 63, wid = tid >> 6;
    const int wr = wid >> 1, wc = wid & 1;

    // A reg-staging addresses: thread covers LDS slots tid (kg=tid>>7) and 256+tid (kg+2)
    // -> global f32 chunks [0..8) and [16..24) relative to gaf.
    const int rowa = tid & 127, kga = tid >> 7;
    const float* gaf = A + (size_t)(brow + rowa) * DIN + kga * 8;
    // B staging (GLL, bf16): thread stages row bcol+tid, 4 chunks k+{0,8,16,24}.
    const unsigned short* gb = Bt + (size_t)(bcol + tid) * DIN;

    f32x4 acc[4][8];
    #pragma unroll
    for (int i = 0; i < 4; i++)
        #pragma unroll
        for (int j = 0; j < 8; j++) acc[i][j] = (f32x4)(0.f);

    // prologue: issue A(0) f32 loads + B(0) GLL into buf 0
    float4 a0 = *(const float4*)(gaf);
    float4 a1 = *(const float4*)(gaf + 4);
    float4 a2 = *(const float4*)(gaf + 16);
    float4 a3 = *(const float4*)(gaf + 20);
    gaf += 32;
    {
        unsigned short* lb = BsF + tid * 8;
        GLL(gb, lb); GLL(gb + 8, lb + 2048); GLL(gb + 16, lb + 4096); GLL(gb + 24, lb + 6144);
        gb += 32;
    }

    const int kg = lane >> 4, r = lane & 15;
    const int NT = DIN / 32;   // 64
    for (int t = 0; t < NT; ++t) {
        const int p = t & 1;
        asm volatile("s_waitcnt vmcnt(0)" ::: "memory");   // A-regs(t) + B(t) landed

        // convert + write A(t) into As[p] (freed by barrier2 of t-1)
        {
            bf16x8 w0, w1;
            w0[0] = (short)f2bf(a0.x); w0[1] = (short)f2bf(a0.y);
            w0[2] = (short)f2bf(a0.z); w0[3] = (short)f2bf(a0.w);
            w0[4] = (short)f2bf(a1.x); w0[5] = (short)f2bf(a1.y);
            w0[6] = (short)f2bf(a1.z); w0[7] = (short)f2bf(a1.w);
            w1[0] = (short)f2bf(a2.x); w1[1] = (short)f2bf(a2.y);
            w1[2] = (short)f2bf(a2.z); w1[3] = (short)f2bf(a2.w);
            w1[4] = (short)f2bf(a3.x); w1[5] = (short)f2bf(a3.y);
            w1[6] = (short)f2bf(a3.z); w1[7] = (short)f2bf(a3.w);
            *(bf16x8*)(AsF + p * ASZ + tid * 8) = w0;
            *(bf16x8*)(AsF + p * ASZ + 2048 + tid * 8) = w1;
        }
        if (t < NT - 1) {
            // issue tile t+1: A f32 -> regs, B -> Bs[p^1] (freed by barrier2 of t-1)
            a0 = *(const float4*)(gaf);
            a1 = *(const float4*)(gaf + 4);
            a2 = *(const float4*)(gaf + 16);
            a3 = *(const float4*)(gaf + 20);
            gaf += 32;
            unsigned short* lb = BsF + (p ^ 1) * BSZ + tid * 8;
            GLL(gb, lb); GLL(gb + 8, lb + 2048); GLL(gb + 16, lb + 4096); GLL(gb + 24, lb + 6144);
            gb += 32;
        }
        asm volatile("s_waitcnt lgkmcnt(0)" ::: "memory");  // my A ds_writes done
        __builtin_amdgcn_s_barrier();                       // A(t), B(t) visible to all
        asm volatile("" ::: "memory");

        const unsigned short* Ab = AsF + p * ASZ;
        const unsigned short* Bb = BsF + p * BSZ;
        bf16x8 af[4], bfm[8];
        #pragma unroll
        for (int mi = 0; mi < 4; mi++)
            af[mi] = *(const bf16x8*)&Ab[(kg * 128 + wr * 64 + mi * 16 + r) * 8];
        #pragma unroll
        for (int ni = 0; ni < 8; ni++)
            bfm[ni] = *(const bf16x8*)&Bb[(kg * 256 + wc * 128 + ni * 16 + r) * 8];
        __builtin_amdgcn_s_setprio(1);
        #pragma unroll
        for (int mi = 0; mi < 4; mi++)
            #pragma unroll
            for (int ni = 0; ni < 8; ni++)
                acc[mi][ni] = __builtin_amdgcn_mfma_f32_16x16x32_bf16(af[mi], bfm[ni], acc[mi][ni], 0, 0, 0);
        __builtin_amdgcn_s_setprio(0);

        asm volatile("" ::: "memory");
        __builtin_amdgcn_s_barrier();   // all waves done reading buf p -> may be restaged
    }

    const int r16 = lane & 15, quad = lane >> 4;
    float bv[8];
    #pragma unroll
    for (int ni = 0; ni < 8; ni++) bv[ni] = bias[bcol + wc * 128 + ni * 16 + r16];

    #pragma unroll
    for (int mi = 0; mi < 4; mi++) {
        float s0 = 0.f, s1 = 0.f, s2 = 0.f, s3 = 0.f;
        #pragma unroll
        for (int j = 0; j < 4; j++) {
            int row = brow + wr * 64 + mi * 16 + quad * 4 + j;
            float sj = 0.f;
            #pragma unroll
            for (int ni = 0; ni < 8; ni++) {
                float e = acc[mi][ni][j] + bv[ni];
                emb_out[(size_t)row * DEMB + bcol + wc * 128 + ni * 16 + r16] = f2bf(e);
                sj += e * e;
            }
            if (j == 0) s0 = sj; else if (j == 1) s1 = sj; else if (j == 2) s2 = sj; else s3 = sj;
        }
        float sv[4] = { s0, s1, s2, s3 };
        #pragma unroll
        for (int j = 0; j < 4; j++) {
            float v = sv[j];
            v += __shfl_xor(v, 1);
            v += __shfl_xor(v, 2);
            v += __shfl_xor(v, 4);
            v += __shfl_xor(v, 8);
            if (r16 == 0) {
                int row = brow + wr * 64 + mi * 16 + quad * 4 + j;
                atomicAdd(&qsq[row], v);
            }
        }
    }
}

// ---------------- support GEMM: r11-verified BM=128/BN=128 2-buf counted-vmcnt ---------
__global__ __launch_bounds__(256, 2) void gemm_support(
    const unsigned short* __restrict__ A,
    const unsigned short* __restrict__ Bt,
    const float* __restrict__ bias,
    const int* __restrict__ labels,
    float* __restrict__ proto_sums)
{
    constexpr int ASZ = 4 * 128 * 8;
    __shared__ __attribute__((aligned(16))) unsigned short AsF[2 * ASZ];
    __shared__ __attribute__((aligned(16))) unsigned short BsF[2 * ASZ];

    const int tid = threadIdx.x;
    const int nblk = DEMB / 128;          // 8
    const int h = blockIdx.x;
    const int cpx = (int)(gridDim.x >> 3);
    const int wg = (h & 7) * cpx + (h >> 3);
    const int bx = wg % nblk, by = wg / nblk;
    const int brow = by * 128, bcol = bx * 128;
    const int lane = tid & 63, wid = tid >> 6;
    const int wr = wid >> 1, wc = wid & 1;

    const int rowa = tid & 127, kga = tid >> 7;
    const unsigned short* ga = A  + (size_t)(brow + rowa) * DIN + kga * 8;
    const unsigned short* gb = Bt + (size_t)(bcol + rowa) * DIN + kga * 8;

    f32x4 acc[4][4];
    #pragma unroll
    for (int i = 0; i < 4; i++)
        #pragma unroll
        for (int j = 0; j < 4; j++) acc[i][j] = (f32x4)(0.f);

    auto stageAB = [&](int buf) {
        unsigned short* la = AsF + buf * ASZ + tid * 8;
        unsigned short* lb = BsF + buf * ASZ + tid * 8;
        GLL(ga, la); GLL(ga + 16, la + 2048);
        GLL(gb, lb); GLL(gb + 16, lb + 2048);
        ga += 32; gb += 32;
    };

    stageAB(0);

    const int kg = lane >> 4, r = lane & 15;
    const int NT = DIN / 32;   // 64
    for (int t = 0; t < NT; ++t) {
        const int cur = t & 1;
        if (t < NT - 1) {
            stageAB(cur ^ 1);
            asm volatile("s_waitcnt vmcnt(4)" ::: "memory");
        } else {
            asm volatile("s_waitcnt vmcnt(0)" ::: "memory");
        }
        __builtin_amdgcn_s_barrier();
        asm volatile("" ::: "memory");

        const unsigned short* Ab = AsF + cur * ASZ;
        const unsigned short* Bb = BsF + cur * ASZ;
        bf16x8 af[4], bfm[4];
        #pragma unroll
        for (int mi = 0; mi < 4; mi++)
            af[mi] = *(const bf16x8*)&Ab[(kg * 128 + wr * 64 + mi * 16 + r) * 8];
        #pragma unroll
        for (int ni = 0; ni < 4; ni++)
            bfm[ni] = *(const bf16x8*)&Bb[(kg * 128 + wc * 64 + ni * 16 + r) * 8];
        #pragma unroll
        for (int mi = 0; mi < 4; mi++)
            #pragma unroll
            for (int ni = 0; ni < 4; ni++)
                acc[mi][ni] = __builtin_amdgcn_mfma_f32_16x16x32_bf16(af[mi], bfm[ni], acc[mi][ni], 0, 0, 0);

        asm volatile("" ::: "memory");
        __builtin_amdgcn_s_barrier();
    }

    const int r16 = lane & 15, quad = lane >> 4;
    float bv[4];
    #pragma unroll
    for (int ni = 0; ni < 4; ni++) bv[ni] = bias[bcol + wc * 64 + ni * 16 + r16];

    #pragma unroll
    for (int mi = 0; mi < 4; mi++) {
        #pragma unroll
        for (int j = 0; j < 4; j++) {
            int row = brow + wr * 64 + mi * 16 + quad * 4 + j;
            int lab = labels[row];
            #pragma unroll
            for (int ni = 0; ni < 4; ni++) {
                float e = acc[mi][ni][j] + bv[ni];
                atomicAdd(&proto_sums[(size_t)lab * DEMB + bcol + wc * 64 + ni * 16 + r16], e);
            }
        }
    }
}

// ---------------- prototype normalize ----------------
__global__ void proto_norm(const float* __restrict__ proto_sums,
                           const int* __restrict__ labels,
                           unsigned short* __restrict__ proto_bf16,
                           float* __restrict__ psq) {
    int c = blockIdx.x;
    int tid = threadIdx.x;
    int cnt = 0;
    for (int i = tid; i < NSUP; i += 256) cnt += (labels[i] == c) ? 1 : 0;
    #pragma unroll
    for (int m = 1; m < 64; m <<= 1) cnt += __shfl_xor(cnt, m);
    __shared__ int warp_cnt[4];
    __shared__ float warp_ss[4];
    if ((tid & 63) == 0) warp_cnt[tid >> 6] = cnt;
    __syncthreads();
    int total = warp_cnt[0] + warp_cnt[1] + warp_cnt[2] + warp_cnt[3];
    float inv = 1.0f / (float)total;
    float ss = 0.f;
    for (int j = tid; j < DEMB; j += 256) {
        float p = proto_sums[(size_t)c * DEMB + j] * inv;
        proto_bf16[(size_t)c * DEMB + j] = f2bf(p);
        ss += p * p;
    }
    #pragma unroll
    for (int m = 1; m < 64; m <<= 1) ss += __shfl_xor(ss, m);
    if ((tid & 63) == 0) warp_ss[tid >> 6] = ss;
    __syncthreads();
    if (tid == 0) psq[c] = warp_ss[0] + warp_ss[1] + warp_ss[2] + warp_ss[3];
}

// ---------------- scores: out[q][c] = -sqrt(max(qsq+psq-2*dot,0)) ----------------
__global__ __launch_bounds__(256) void scores_kernel(
    const unsigned short* __restrict__ q_emb,
    const unsigned short* __restrict__ protos,
    const float* __restrict__ qsq, const float* __restrict__ psq,
    float* __restrict__ out)
{
    int tid = threadIdx.x, lane = tid & 63, wid = tid >> 6;
    int q0 = blockIdx.x * 64 + wid * 16;
    int r = lane & 15, quad = lane >> 4;
    f32x4 acc[4];
    #pragma unroll
    for (int i = 0; i < 4; i++) acc[i] = (f32x4)(0.f);
    const unsigned short* arow = q_emb + (size_t)(q0 + r) * DEMB + quad * 8;
    for (int k0 = 0; k0 < DEMB; k0 += 32) {
        bf16x8 a = *(const bf16x8*)(arow + k0);
        #pragma unroll
        for (int ni = 0; ni < 4; ni++) {
            bf16x8 bfrag = *(const bf16x8*)(protos + (size_t)(ni * 16 + r) * DEMB + k0 + quad * 8);
            acc[ni] = __builtin_amdgcn_mfma_f32_16x16x32_bf16(a, bfrag, acc[ni], 0, 0, 0);
        }
    }
    #pragma unroll
    for (int ni = 0; ni < 4; ni++) {
        int c = ni * 16 + r;
        float ps = psq[c];
        #pragma unroll
        for (int j = 0; j < 4; j++) {
            int row = q0 + quad * 4 + j;
            float d2 = qsq[row] + ps - 2.0f * acc[ni][j];
            d2 = fmaxf(d2, 0.0f);
            out[(size_t)row * NWAY + c] = -sqrtf(d2);
        }
    }
}

// ---------------- launch ----------------
extern "C" void kernel_launch(void* const* d_in, const int* in_sizes, int n_in,
                              void* d_out, int out_size, void* d_ws, size_t ws_size,
                              hipStream_t stream) {
    const float* support = (const float*)d_in[0];
    const float* query   = (const float*)d_in[1];
    const int*   labels  = (const int*)d_in[2];
    // d_in[3] = n_way (assumed 64)
    const float* W       = (const float*)d_in[4];
    const float* bias    = (const float*)d_in[5];
    float* out = (float*)d_out;

    char* ws = (char*)d_ws;
    unsigned short* s_bf     = (unsigned short*)(ws + 67108864);      //  8388608 B
    unsigned short* Wt       = (unsigned short*)(ws + 75497472);      //  4194304 B
    unsigned short* q_emb    = (unsigned short*)(ws + 79691776);      // 33554432 B
    float*          proto_sums = (float*)(ws + 113246208);            //   262144 B
    unsigned short* proto_bf = (unsigned short*)(ws + 113508352);     //   131072 B
    float*          qsq      = (float*)(ws + 113639424);              //    65536 B
    float*          psq      = (float*)(ws + 113704960);              //      256 B

    hipMemsetAsync(proto_sums, 0, (size_t)NWAY * DEMB * sizeof(float), stream);
    hipMemsetAsync(qsq, 0, (size_t)NQRY * sizeof(float), stream);

    cvt_f32_bf16<<<512, 256, 0, stream>>>(support, s_bf, NSUP * DIN);
    dim3 tg(DEMB / 32, DIN / 32);
    cvt_transpose<<<tg, 256, 0, stream>>>(W, Wt);

    gemm_support<<<(NSUP / 128) * (DEMB / 128), 256, 0, stream>>>(
        s_bf, Wt, bias, labels, proto_sums);
    proto_norm<<<NWAY, 256, 0, stream>>>(proto_sums, labels, proto_bf, psq);
    gemm_query<<<(NQRY / 128) * (DEMB / 256), 256, 0, stream>>>(
        query, Wt, bias, q_emb, qsq);
    scores_kernel<<<NQRY / 64, 256, 0, stream>>>(q_emb, proto_bf, qsq, psq, out);
}

// Round 15
// 256.146 us; speedup vs baseline: 1.1392x; 1.0014x over previous
//
#include <hip/hip_runtime.h>
#include <hip/hip_bf16.h>
#include <stdint.h>

#define DIN 2048
#define DEMB 1024
#define NSUP 2048
#define NQRY 16384
#define NWAY 64

typedef __attribute__((ext_vector_type(8))) short bf16x8;
typedef __attribute__((ext_vector_type(4))) float f32x4;

__device__ inline unsigned short f2bf(float f) {
    union { float f; uint32_t u; } v; v.f = f;
    uint32_t u = v.u;
    uint32_t r = (u + 0x7FFFu + ((u >> 16) & 1u)) >> 16;
    return (unsigned short)r;
}

#define GLL(g, l) __builtin_amdgcn_global_load_lds(                                   \
    (const __attribute__((address_space(1))) void*)(g),                               \
    (__attribute__((address_space(3))) void*)(l), 16, 0, 0)

// ---------------- conversion kernels ----------------

__global__ void cvt_f32_bf16(const float* __restrict__ in, unsigned short* __restrict__ out, int n) {
    int i = (blockIdx.x * blockDim.x + threadIdx.x) * 4;
    int stride = gridDim.x * blockDim.x * 4;
    for (; i < n; i += stride) {
        float4 v = *(const float4*)(in + i);
        ushort4 o;
        o.x = f2bf(v.x); o.y = f2bf(v.y); o.z = f2bf(v.z); o.w = f2bf(v.w);
        *(ushort4*)(out + i) = o;
    }
}

// W [DIN][DEMB] f32  ->  Wt [DEMB][DIN] bf16
__global__ void cvt_transpose(const float* __restrict__ W, unsigned short* __restrict__ Wt) {
    __shared__ float tile[32][33];
    int c0 = blockIdx.x * 32;
    int r0 = blockIdx.y * 32;
    int tc = threadIdx.x & 31, tr = threadIdx.x >> 5;
    #pragma unroll
    for (int i = 0; i < 4; i++)
        tile[tr + 8*i][tc] = W[(size_t)(r0 + tr + 8*i) * DEMB + c0 + tc];
    __syncthreads();
    #pragma unroll
    for (int i = 0; i < 4; i++)
        Wt[(size_t)(c0 + tr + 8*i) * DIN + r0 + tc] = f2bf(tile[tc][tr + 8*i]);
}

// ---------------- query GEMM: BM=128, BN=256, BK=32, 2-buf, fused A-convert ----------
// COUNTED vmcnt discipline (r14 fix): in-order vmcnt retirement means
//   loop top:  outstanding [A(t)x4, B(t)x4]      -> vmcnt(4): A(t) regs landed (convert ok)
//   after issuing A(t+1)+B(t+1):  [B(t)x4, A(t+1)x4, B(t+1)x4] -> vmcnt(8): B(t) in LDS,
//   tile t+1's 8 loads stay in flight ACROSS the barrier (never drain to 0 mid-loop).
// lgkmcnt(0) before barrier makes this wave's A ds_writes visible to all.
__global__ __launch_bounds__(256, 2) void gemm_query(
    const float* __restrict__ A,              // f32 [NQRY][DIN]
    const unsigned short* __restrict__ Bt,    // bf16 [DEMB][DIN]
    const float* __restrict__ bias,
    unsigned short* __restrict__ emb_out,
    float* __restrict__ qsq)
{
    constexpr int ASZ = 4 * 128 * 8;          // 4096 elems/buf (8 KB)
    constexpr int BSZ = 4 * 256 * 8;          // 8192 elems/buf (16 KB)
    __shared__ __attribute__((aligned(16))) unsigned short AsF[2 * ASZ];
    __shared__ __attribute__((aligned(16))) unsigned short BsF[2 * BSZ];

    const int tid = threadIdx.x;
    const int nblk = DEMB / 256;              // 4
    // XCD-panel grouping (verified r8). gridDim.x = 512, %8 == 0.
    const int h = blockIdx.x;
    const int cpx = (int)(gridDim.x >> 3);
    const int wg = (h & 7) * cpx + (h >> 3);
    const int bx = wg % nblk, by = wg / nblk;
    const int brow = by * 128, bcol = bx * 256;
    const int lane = tid & 63, wid = tid >> 6;
    const int wr = wid >> 1, wc = wid & 1;

    // A reg-staging: thread covers LDS slots tid (kg=tid>>7) and 256+tid (kg+2)
    // -> global f32 chunks [0..8) and [16..24) relative to gaf.
    const int rowa = tid & 127, kga = tid >> 7;
    const float* gaf = A + (size_t)(brow + rowa) * DIN + kga * 8;
    // B staging (GLL, bf16): thread stages row bcol+tid, 4 chunks k+{0,8,16,24}.
    const unsigned short* gb = Bt + (size_t)(bcol + tid) * DIN;

    f32x4 acc[4][8];
    #pragma unroll
    for (int i = 0; i < 4; i++)
        #pragma unroll
        for (int j = 0; j < 8; j++) acc[i][j] = (f32x4)(0.f);

    // prologue: issue A(0) f32 loads + B(0) GLL into buf 0
    float4 a0 = *(const float4*)(gaf);
    float4 a1 = *(const float4*)(gaf + 4);
    float4 a2 = *(const float4*)(gaf + 16);
    float4 a3 = *(const float4*)(gaf + 20);
    gaf += 32;
    {
        unsigned short* lb = BsF + tid * 8;
        GLL(gb, lb); GLL(gb + 8, lb + 2048); GLL(gb + 16, lb + 4096); GLL(gb + 24, lb + 6144);
        gb += 32;
    }

    const int kg = lane >> 4, r = lane & 15;
    const int NT = DIN / 32;   // 64
    for (int t = 0; t < NT; ++t) {
        const int p = t & 1;
        // A(t) regs landed (oldest 4 of [A(t)x4, B(t)x4]); B(t) may still be in flight
        asm volatile("s_waitcnt vmcnt(4)" ::: "memory");

        // convert + write A(t) into As[p] (freed by barrier2 of t-1)
        {
            bf16x8 w0, w1;
            w0[0] = (short)f2bf(a0.x); w0[1] = (short)f2bf(a0.y);
            w0[2] = (short)f2bf(a0.z); w0[3] = (short)f2bf(a0.w);
            w0[4] = (short)f2bf(a1.x); w0[5] = (short)f2bf(a1.y);
            w0[6] = (short)f2bf(a1.z); w0[7] = (short)f2bf(a1.w);
            w1[0] = (short)f2bf(a2.x); w1[1] = (short)f2bf(a2.y);
            w1[2] = (short)f2bf(a2.z); w1[3] = (short)f2bf(a2.w);
            w1[4] = (short)f2bf(a3.x); w1[5] = (short)f2bf(a3.y);
            w1[6] = (short)f2bf(a3.z); w1[7] = (short)f2bf(a3.w);
            *(bf16x8*)(AsF + p * ASZ + tid * 8) = w0;
            *(bf16x8*)(AsF + p * ASZ + 2048 + tid * 8) = w1;
        }
        if (t < NT - 1) {
            // issue tile t+1: A f32 -> regs, B -> Bs[p^1] (freed by barrier2 of t-1)
            a0 = *(const float4*)(gaf);
            a1 = *(const float4*)(gaf + 4);
            a2 = *(const float4*)(gaf + 16);
            a3 = *(const float4*)(gaf + 20);
            gaf += 32;
            unsigned short* lb = BsF + (p ^ 1) * BSZ + tid * 8;
            GLL(gb, lb); GLL(gb + 8, lb + 2048); GLL(gb + 16, lb + 4096); GLL(gb + 24, lb + 6144);
            gb += 32;
            // B(t) landed; A(t+1)+B(t+1) (8 newest) stay in flight across the barrier
            asm volatile("s_waitcnt vmcnt(8)" ::: "memory");
        } else {
            asm volatile("s_waitcnt vmcnt(0)" ::: "memory");   // last tile: drain B(t)
        }
        asm volatile("s_waitcnt lgkmcnt(0)" ::: "memory");  // my A ds_writes done
        __builtin_amdgcn_s_barrier();                       // A(t), B(t) visible to all
        asm volatile("" ::: "memory");

        const unsigned short* Ab = AsF + p * ASZ;
        const unsigned short* Bb = BsF + p * BSZ;
        bf16x8 af[4], bfm[8];
        #pragma unroll
        for (int mi = 0; mi < 4; mi++)
            af[mi] = *(const bf16x8*)&Ab[(kg * 128 + wr * 64 + mi * 16 + r) * 8];
        #pragma unroll
        for (int ni = 0; ni < 8; ni++)
            bfm[ni] = *(const bf16x8*)&Bb[(kg * 256 + wc * 128 + ni * 16 + r) * 8];
        __builtin_amdgcn_s_setprio(1);
        #pragma unroll
        for (int mi = 0; mi < 4; mi++)
            #pragma unroll
            for (int ni = 0; ni < 8; ni++)
                acc[mi][ni] = __builtin_amdgcn_mfma_f32_16x16x32_bf16(af[mi], bfm[ni], acc[mi][ni], 0, 0, 0);
        __builtin_amdgcn_s_setprio(0);

        asm volatile("" ::: "memory");
        __builtin_amdgcn_s_barrier();   // all waves done reading buf p -> may be restaged
    }

    const int r16 = lane & 15, quad = lane >> 4;
    float bv[8];
    #pragma unroll
    for (int ni = 0; ni < 8; ni++) bv[ni] = bias[bcol + wc * 128 + ni * 16 + r16];

    #pragma unroll
    for (int mi = 0; mi < 4; mi++) {
        float s0 = 0.f, s1 = 0.f, s2 = 0.f, s3 = 0.f;
        #pragma unroll
        for (int j = 0; j < 4; j++) {
            int row = brow + wr * 64 + mi * 16 + quad * 4 + j;
            float sj = 0.f;
            #pragma unroll
            for (int ni = 0; ni < 8; ni++) {
                float e = acc[mi][ni][j] + bv[ni];
                emb_out[(size_t)row * DEMB + bcol + wc * 128 + ni * 16 + r16] = f2bf(e);
                sj += e * e;
            }
            if (j == 0) s0 = sj; else if (j == 1) s1 = sj; else if (j == 2) s2 = sj; else s3 = sj;
        }
        float sv[4] = { s0, s1, s2, s3 };
        #pragma unroll
        for (int j = 0; j < 4; j++) {
            float v = sv[j];
            v += __shfl_xor(v, 1);
            v += __shfl_xor(v, 2);
            v += __shfl_xor(v, 4);
            v += __shfl_xor(v, 8);
            if (r16 == 0) {
                int row = brow + wr * 64 + mi * 16 + quad * 4 + j;
                atomicAdd(&qsq[row], v);
            }
        }
    }
}

// ---------------- support GEMM: r11-verified BM=128/BN=128 2-buf counted-vmcnt ---------
__global__ __launch_bounds__(256, 2) void gemm_support(
    const unsigned short* __restrict__ A,
    const unsigned short* __restrict__ Bt,
    const float* __restrict__ bias,
    const int* __restrict__ labels,
    float* __restrict__ proto_sums)
{
    constexpr int ASZ = 4 * 128 * 8;
    __shared__ __attribute__((aligned(16))) unsigned short AsF[2 * ASZ];
    __shared__ __attribute__((aligned(16))) unsigned short BsF[2 * ASZ];

    const int tid = threadIdx.x;
    const int nblk = DEMB / 128;          // 8
    const int h = blockIdx.x;
    const int cpx = (int)(gridDim.x >> 3);
    const int wg = (h & 7) * cpx + (h >> 3);
    const int bx = wg % nblk, by = wg / nblk;
    const int brow = by * 128, bcol = bx * 128;
    const int lane = tid & 63, wid = tid >> 6;
    const int wr = wid >> 1, wc = wid & 1;

    const int rowa = tid & 127, kga = tid >> 7;
    const unsigned short* ga = A  + (size_t)(brow + rowa) * DIN + kga * 8;
    const unsigned short* gb = Bt + (size_t)(bcol + rowa) * DIN + kga * 8;

    f32x4 acc[4][4];
    #pragma unroll
    for (int i = 0; i < 4; i++)
        #pragma unroll
        for (int j = 0; j < 4; j++) acc[i][j] = (f32x4)(0.f);

    auto stageAB = [&](int buf) {
        unsigned short* la = AsF + buf * ASZ + tid * 8;
        unsigned short* lb = BsF + buf * ASZ + tid * 8;
        GLL(ga, la); GLL(ga + 16, la + 2048);
        GLL(gb, lb); GLL(gb + 16, lb + 2048);
        ga += 32; gb += 32;
    };

    stageAB(0);

    const int kg = lane >> 4, r = lane & 15;
    const int NT = DIN / 32;   // 64
    for (int t = 0; t < NT; ++t) {
        const int cur = t & 1;
        if (t < NT - 1) {
            stageAB(cur ^ 1);
            asm volatile("s_waitcnt vmcnt(4)" ::: "memory");
        } else {
            asm volatile("s_waitcnt vmcnt(0)" ::: "memory");
        }
        __builtin_amdgcn_s_barrier();
        asm volatile("" ::: "memory");

        const unsigned short* Ab = AsF + cur * ASZ;
        const unsigned short* Bb = BsF + cur * ASZ;
        bf16x8 af[4], bfm[4];
        #pragma unroll
        for (int mi = 0; mi < 4; mi++)
            af[mi] = *(const bf16x8*)&Ab[(kg * 128 + wr * 64 + mi * 16 + r) * 8];
        #pragma unroll
        for (int ni = 0; ni < 4; ni++)
            bfm[ni] = *(const bf16x8*)&Bb[(kg * 128 + wc * 64 + ni * 16 + r) * 8];
        #pragma unroll
        for (int mi = 0; mi < 4; mi++)
            #pragma unroll
            for (int ni = 0; ni < 4; ni++)
                acc[mi][ni] = __builtin_amdgcn_mfma_f32_16x16x32_bf16(af[mi], bfm[ni], acc[mi][ni], 0, 0, 0);

        asm volatile("" ::: "memory");
        __builtin_amdgcn_s_barrier();
    }

    const int r16 = lane & 15, quad = lane >> 4;
    float bv[4];
    #pragma unroll
    for (int ni = 0; ni < 4; ni++) bv[ni] = bias[bcol + wc * 64 + ni * 16 + r16];

    #pragma unroll
    for (int mi = 0; mi < 4; mi++) {
        #pragma unroll
        for (int j = 0; j < 4; j++) {
            int row = brow + wr * 64 + mi * 16 + quad * 4 + j;
            int lab = labels[row];
            #pragma unroll
            for (int ni = 0; ni < 4; ni++) {
                float e = acc[mi][ni][j] + bv[ni];
                atomicAdd(&proto_sums[(size_t)lab * DEMB + bcol + wc * 64 + ni * 16 + r16], e);
            }
        }
    }
}

// ---------------- prototype normalize ----------------
__global__ void proto_norm(const float* __restrict__ proto_sums,
                           const int* __restrict__ labels,
                           unsigned short* __restrict__ proto_bf16,
                           float* __restrict__ psq) {
    int c = blockIdx.x;
    int tid = threadIdx.x;
    int cnt = 0;
    for (int i = tid; i < NSUP; i += 256) cnt += (labels[i] == c) ? 1 : 0;
    #pragma unroll
    for (int m = 1; m < 64; m <<= 1) cnt += __shfl_xor(cnt, m);
    __shared__ int warp_cnt[4];
    __shared__ float warp_ss[4];
    if ((tid & 63) == 0) warp_cnt[tid >> 6] = cnt;
    __syncthreads();
    int total = warp_cnt[0] + warp_cnt[1] + warp_cnt[2] + warp_cnt[3];
    float inv = 1.0f / (float)total;
    float ss = 0.f;
    for (int j = tid; j < DEMB; j += 256) {
        float p = proto_sums[(size_t)c * DEMB + j] * inv;
        proto_bf16[(size_t)c * DEMB + j] = f2bf(p);
        ss += p * p;
    }
    #pragma unroll
    for (int m = 1; m < 64; m <<= 1) ss += __shfl_xor(ss, m);
    if ((tid & 63) == 0) warp_ss[tid >> 6] = ss;
    __syncthreads();
    if (tid == 0) psq[c] = warp_ss[0] + warp_ss[1] + warp_ss[2] + warp_ss[3];
}

// ---------------- scores: out[q][c] = -sqrt(max(qsq+psq-2*dot,0)) ----------------
__global__ __launch_bounds__(256) void scores_kernel(
    const unsigned short* __restrict__ q_emb,
    const unsigned short* __restrict__ protos,
    const float* __restrict__ qsq, const float* __restrict__ psq,
    float* __restrict__ out)
{
    int tid = threadIdx.x, lane = tid & 63, wid = tid >> 6;
    int q0 = blockIdx.x * 64 + wid * 16;
    int r = lane & 15, quad = lane >> 4;
    f32x4 acc[4];
    #pragma unroll
    for (int i = 0; i < 4; i++) acc[i] = (f32x4)(0.f);
    const unsigned short* arow = q_emb + (size_t)(q0 + r) * DEMB + quad * 8;
    for (int k0 = 0; k0 < DEMB; k0 += 32) {
        bf16x8 a = *(const bf16x8*)(arow + k0);
        #pragma unroll
        for (int ni = 0; ni < 4; ni++) {
            bf16x8 bfrag = *(const bf16x8*)(protos + (size_t)(ni * 16 + r) * DEMB + k0 + quad * 8);
            acc[ni] = __builtin_amdgcn_mfma_f32_16x16x32_bf16(a, bfrag, acc[ni], 0, 0, 0);
        }
    }
    #pragma unroll
    for (int ni = 0; ni < 4; ni++) {
        int c = ni * 16 + r;
        float ps = psq[c];
        #pragma unroll
        for (int j = 0; j < 4; j++) {
            int row = q0 + quad * 4 + j;
            float d2 = qsq[row] + ps - 2.0f * acc[ni][j];
            d2 = fmaxf(d2, 0.0f);
            out[(size_t)row * NWAY + c] = -sqrtf(d2);
        }
    }
}

// ---------------- launch ----------------
extern "C" void kernel_launch(void* const* d_in, const int* in_sizes, int n_in,
                              void* d_out, int out_size, void* d_ws, size_t ws_size,
                              hipStream_t stream) {
    const float* support = (const float*)d_in[0];
    const float* query   = (const float*)d_in[1];
    const int*   labels  = (const int*)d_in[2];
    // d_in[3] = n_way (assumed 64)
    const float* W       = (const float*)d_in[4];
    const float* bias    = (const float*)d_in[5];
    float* out = (float*)d_out;

    char* ws = (char*)d_ws;
    unsigned short* s_bf     = (unsigned short*)(ws + 67108864);      //  8388608 B
    unsigned short* Wt       = (unsigned short*)(ws + 75497472);      //  4194304 B
    unsigned short* q_emb    = (unsigned short*)(ws + 79691776);      // 33554432 B
    float*          proto_sums = (float*)(ws + 113246208);            //   262144 B
    unsigned short* proto_bf = (unsigned short*)(ws + 113508352);     //   131072 B
    float*          qsq      = (float*)(ws + 113639424);              //    65536 B
    float*          psq      = (float*)(ws + 113704960);              //      256 B

    hipMemsetAsync(proto_sums, 0, (size_t)NWAY * DEMB * sizeof(float), stream);
    hipMemsetAsync(qsq, 0, (size_t)NQRY * sizeof(float), stream);

    cvt_f32_bf16<<<512, 256, 0, stream>>>(support, s_bf, NSUP * DIN);
    dim3 tg(DEMB / 32, DIN / 32);
    cvt_transpose<<<tg, 256, 0, stream>>>(W, Wt);

    gemm_support<<<(NSUP / 128) * (DEMB / 128), 256, 0, stream>>>(
        s_bf, Wt, bias, labels, proto_sums);
    proto_norm<<<NWAY, 256, 0, stream>>>(proto_sums, labels, proto_bf, psq);
    gemm_query<<<(NQRY / 128) * (DEMB / 256), 256, 0, stream>>>(
        query, Wt, bias, q_emb, qsq);
    scores_kernel<<<NQRY / 64, 256, 0, stream>>>(q_emb, proto_bf, qsq, psq, out);
}

// Round 16
// 235.625 us; speedup vs baseline: 1.2384x; 1.0871x over previous
//
#include <hip/hip_runtime.h>
#include <hip/hip_bf16.h>
#include <stdint.h>

#define DIN 2048
#define DEMB 1024
#define NSUP 2048
#define NQRY 16384
#define NWAY 64

typedef __attribute__((ext_vector_type(8))) short bf16x8;
typedef __attribute__((ext_vector_type(4))) float f32x4;

__device__ inline unsigned short f2bf(float f) {
    union { float f; uint32_t u; } v; v.f = f;
    uint32_t u = v.u;
    uint32_t r = (u + 0x7FFFu + ((u >> 16) & 1u)) >> 16;
    return (unsigned short)r;
}

#define GLL(g, l) __builtin_amdgcn_global_load_lds(                                   \
    (const __attribute__((address_space(1))) void*)(g),                               \
    (__attribute__((address_space(3))) void*)(l), 16, 0, 0)

// ---------------- conversion kernels ----------------

__global__ void cvt_f32_bf16(const float* __restrict__ in, unsigned short* __restrict__ out, int n) {
    int i = (blockIdx.x * blockDim.x + threadIdx.x) * 4;
    int stride = gridDim.x * blockDim.x * 4;
    for (; i < n; i += stride) {
        float4 v = *(const float4*)(in + i);
        ushort4 o;
        o.x = f2bf(v.x); o.y = f2bf(v.y); o.z = f2bf(v.z); o.w = f2bf(v.w);
        *(ushort4*)(out + i) = o;
    }
}

// W [DIN][DEMB] f32  ->  Wt [DEMB][DIN] bf16
__global__ void cvt_transpose(const float* __restrict__ W, unsigned short* __restrict__ Wt) {
    __shared__ float tile[32][33];
    int c0 = blockIdx.x * 32;
    int r0 = blockIdx.y * 32;
    int tc = threadIdx.x & 31, tr = threadIdx.x >> 5;
    #pragma unroll
    for (int i = 0; i < 4; i++)
        tile[tr + 8*i][tc] = W[(size_t)(r0 + tr + 8*i) * DEMB + c0 + tc];
    __syncthreads();
    #pragma unroll
    for (int i = 0; i < 4; i++)
        Wt[(size_t)(c0 + tr + 8*i) * DIN + r0 + tc] = f2bf(tile[tc][tr + 8*i]);
}

// ---------------- embedding GEMM: BM=128, BN=32*NNI, BK=32, 3-buf SINGLE-BARRIER ------
// r11 structure (verified 126us/22% MfmaUtil) with barrier #2 removed via triple buffer.
// Race audit (single barrier per K-step):
//  * stage(t+1) -> buf (t+1)%3, issued by wave X between barrier(t-1) and barrier(t).
//  * buf (t+1)%3 was last READ at tile t-2 by wave Y, inside Y's compute(t-2);
//    Y's ds_reads complete before Y issues its MFMAs (compiler lgkmcnt), which precede
//    Y's barrier(t-1) in program order. X issues stage(t+1) only after passing
//    barrier(t-1), by which point ALL waves' tile-(t-2) reads have landed.  -> no WAR race.
//  * Readers of stage(t+1): tile t+1 compute, after barrier(t+1); vmcnt at iter t+1
//    (after issuing stage(t+2)) waits until only stage(t+2) remains outstanding, i.e.
//    stage(t+1) fully in LDS before barrier(t+1).                            -> no RAW race.
//  * Counted vmcnt steady state: 2 stages in flight, wait leaves 1 (never 0 mid-loop).
// EPILOGUE 0: support -> atomicAdd proto_sums[label[row]][col]
// EPILOGUE 1: query   -> store bf16 emb + atomicAdd row sumsq

template<int EPILOGUE, int NNI>
__global__ __launch_bounds__(256, 2) void gemm_emb(
    const unsigned short* __restrict__ A,
    const unsigned short* __restrict__ Bt,
    const float* __restrict__ bias,
    const int* __restrict__ labels,
    float* __restrict__ proto_sums,
    unsigned short* __restrict__ emb_out,
    float* __restrict__ qsq)
{
    constexpr int BN = 32 * NNI;          // 256 (query) or 128 (support)
    constexpr int ASZ = 4 * 128 * 8;      // 4096 elems / buf
    constexpr int BSZ = 4 * BN * 8;       // 8192 or 4096 elems / buf
    __shared__ __attribute__((aligned(16))) unsigned short AsF[3 * ASZ];
    __shared__ __attribute__((aligned(16))) unsigned short BsF[3 * BSZ];

    const int tid = threadIdx.x;
    const int nblk = DEMB / BN;           // 4 (query) or 8 (support)
    // XCD-panel grouping (verified r8: FETCH 268->66MB). gridDim.x % 8 == 0.
    const int h = blockIdx.x;
    const int cpx = (int)(gridDim.x >> 3);
    const int wg = (h & 7) * cpx + (h >> 3);
    const int bx = wg % nblk, by = wg / nblk;
    const int brow = by * 128, bcol = bx * BN;
    const int lane = tid & 63, wid = tid >> 6;
    const int wr = wid >> 1, wc = wid & 1;

    // hoisted staging pointers
    const int rowa = tid & 127, kga = tid >> 7;
    const unsigned short* ga = A + (size_t)(brow + rowa) * DIN + kga * 8;
    const unsigned short* gb;
    if constexpr (NNI == 8) {
        gb = Bt + (size_t)(bcol + tid) * DIN;              // 4 loads: +0,8,16,24 elems
    } else {
        gb = Bt + (size_t)(bcol + rowa) * DIN + kga * 8;   // 2 loads: +0,+16 elems
    }

    f32x4 acc[4][NNI];
    #pragma unroll
    for (int i = 0; i < 4; i++)
        #pragma unroll
        for (int j = 0; j < NNI; j++) acc[i][j] = (f32x4)(0.f);

    auto stageAB = [&](int buf) {
        unsigned short* la = AsF + buf * ASZ + tid * 8;
        unsigned short* lb = BsF + buf * BSZ + tid * 8;
        GLL(ga, la); GLL(ga + 16, la + 2048);
        if constexpr (NNI == 8) {
            GLL(gb, lb); GLL(gb + 8, lb + 2048); GLL(gb + 16, lb + 4096); GLL(gb + 24, lb + 6144);
        } else {
            GLL(gb, lb); GLL(gb + 16, lb + 2048);
        }
        ga += 32; gb += 32;
    };

    stageAB(0);   // prologue: tile 0 -> buf 0

    const int kg = lane >> 4, r = lane & 15;
    const int NT = DIN / 32;   // 64
    int cur = 0, nxt = 1;
    for (int t = 0; t < NT; ++t) {
        if (t < NT - 1) {
            stageAB(nxt);   // stays in flight across the barrier
            if constexpr (NNI == 8) asm volatile("s_waitcnt vmcnt(6)" ::: "memory");
            else                    asm volatile("s_waitcnt vmcnt(4)" ::: "memory");
        } else {
            asm volatile("s_waitcnt vmcnt(0)" ::: "memory");
        }
        __builtin_amdgcn_s_barrier();        // single rendezvous per K-step
        asm volatile("" ::: "memory");

        const unsigned short* Ab = AsF + cur * ASZ;
        const unsigned short* Bb = BsF + cur * BSZ;
        bf16x8 af[4], bfm[NNI];
        #pragma unroll
        for (int mi = 0; mi < 4; mi++)
            af[mi] = *(const bf16x8*)&Ab[(kg * 128 + wr * 64 + mi * 16 + r) * 8];
        #pragma unroll
        for (int ni = 0; ni < NNI; ni++)
            bfm[ni] = *(const bf16x8*)&Bb[(kg * BN + wc * (BN / 2) + ni * 16 + r) * 8];
        __builtin_amdgcn_s_setprio(1);
        #pragma unroll
        for (int mi = 0; mi < 4; mi++)
            #pragma unroll
            for (int ni = 0; ni < NNI; ni++)
                acc[mi][ni] = __builtin_amdgcn_mfma_f32_16x16x32_bf16(af[mi], bfm[ni], acc[mi][ni], 0, 0, 0);
        __builtin_amdgcn_s_setprio(0);
        asm volatile("" ::: "memory");

        cur = (cur == 2) ? 0 : cur + 1;
        nxt = (nxt == 2) ? 0 : nxt + 1;
    }

    const int r16 = lane & 15, quad = lane >> 4;
    float bv[NNI];
    #pragma unroll
    for (int ni = 0; ni < NNI; ni++) bv[ni] = bias[bcol + wc * (BN / 2) + ni * 16 + r16];

    if (EPILOGUE == 0) {
        #pragma unroll
        for (int mi = 0; mi < 4; mi++) {
            #pragma unroll
            for (int j = 0; j < 4; j++) {
                int row = brow + wr * 64 + mi * 16 + quad * 4 + j;
                int lab = labels[row];
                #pragma unroll
                for (int ni = 0; ni < NNI; ni++) {
                    float e = acc[mi][ni][j] + bv[ni];
                    atomicAdd(&proto_sums[(size_t)lab * DEMB + bcol + wc * (BN / 2) + ni * 16 + r16], e);
                }
            }
        }
    } else {
        #pragma unroll
        for (int mi = 0; mi < 4; mi++) {
            float s0 = 0.f, s1 = 0.f, s2 = 0.f, s3 = 0.f;
            #pragma unroll
            for (int j = 0; j < 4; j++) {
                int row = brow + wr * 64 + mi * 16 + quad * 4 + j;
                float sj = 0.f;
                #pragma unroll
                for (int ni = 0; ni < NNI; ni++) {
                    float e = acc[mi][ni][j] + bv[ni];
                    emb_out[(size_t)row * DEMB + bcol + wc * (BN / 2) + ni * 16 + r16] = f2bf(e);
                    sj += e * e;
                }
                if (j == 0) s0 = sj; else if (j == 1) s1 = sj; else if (j == 2) s2 = sj; else s3 = sj;
            }
            float sv[4] = { s0, s1, s2, s3 };
            #pragma unroll
            for (int j = 0; j < 4; j++) {
                float v = sv[j];
                v += __shfl_xor(v, 1);
                v += __shfl_xor(v, 2);
                v += __shfl_xor(v, 4);
                v += __shfl_xor(v, 8);
                if (r16 == 0) {
                    int row = brow + wr * 64 + mi * 16 + quad * 4 + j;
                    atomicAdd(&qsq[row], v);
                }
            }
        }
    }
}

// ---------------- prototype normalize ----------------
__global__ void proto_norm(const float* __restrict__ proto_sums,
                           const int* __restrict__ labels,
                           unsigned short* __restrict__ proto_bf16,
                           float* __restrict__ psq) {
    int c = blockIdx.x;
    int tid = threadIdx.x;
    int cnt = 0;
    for (int i = tid; i < NSUP; i += 256) cnt += (labels[i] == c) ? 1 : 0;
    #pragma unroll
    for (int m = 1; m < 64; m <<= 1) cnt += __shfl_xor(cnt, m);
    __shared__ int warp_cnt[4];
    __shared__ float warp_ss[4];
    if ((tid & 63) == 0) warp_cnt[tid >> 6] = cnt;
    __syncthreads();
    int total = warp_cnt[0] + warp_cnt[1] + warp_cnt[2] + warp_cnt[3];
    float inv = 1.0f / (float)total;
    float ss = 0.f;
    for (int j = tid; j < DEMB; j += 256) {
        float p = proto_sums[(size_t)c * DEMB + j] * inv;
        proto_bf16[(size_t)c * DEMB + j] = f2bf(p);
        ss += p * p;
    }
    #pragma unroll
    for (int m = 1; m < 64; m <<= 1) ss += __shfl_xor(ss, m);
    if ((tid & 63) == 0) warp_ss[tid >> 6] = ss;
    __syncthreads();
    if (tid == 0) psq[c] = warp_ss[0] + warp_ss[1] + warp_ss[2] + warp_ss[3];
}

// ---------------- scores: out[q][c] = -sqrt(max(qsq+psq-2*dot,0)) ----------------
__global__ __launch_bounds__(256) void scores_kernel(
    const unsigned short* __restrict__ q_emb,
    const unsigned short* __restrict__ protos,
    const float* __restrict__ qsq, const float* __restrict__ psq,
    float* __restrict__ out)
{
    int tid = threadIdx.x, lane = tid & 63, wid = tid >> 6;
    int q0 = blockIdx.x * 64 + wid * 16;
    int r = lane & 15, quad = lane >> 4;
    f32x4 acc[4];
    #pragma unroll
    for (int i = 0; i < 4; i++) acc[i] = (f32x4)(0.f);
    const unsigned short* arow = q_emb + (size_t)(q0 + r) * DEMB + quad * 8;
    for (int k0 = 0; k0 < DEMB; k0 += 32) {
        bf16x8 a = *(const bf16x8*)(arow + k0);
        #pragma unroll
        for (int ni = 0; ni < 4; ni++) {
            bf16x8 bfrag = *(const bf16x8*)(protos + (size_t)(ni * 16 + r) * DEMB + k0 + quad * 8);
            acc[ni] = __builtin_amdgcn_mfma_f32_16x16x32_bf16(a, bfrag, acc[ni], 0, 0, 0);
        }
    }
    #pragma unroll
    for (int ni = 0; ni < 4; ni++) {
        int c = ni * 16 + r;
        float ps = psq[c];
        #pragma unroll
        for (int j = 0; j < 4; j++) {
            int row = q0 + quad * 4 + j;
            float d2 = qsq[row] + ps - 2.0f * acc[ni][j];
            d2 = fmaxf(d2, 0.0f);
            out[(size_t)row * NWAY + c] = -sqrtf(d2);
        }
    }
}

// ---------------- launch ----------------
extern "C" void kernel_launch(void* const* d_in, const int* in_sizes, int n_in,
                              void* d_out, int out_size, void* d_ws, size_t ws_size,
                              hipStream_t stream) {
    const float* support = (const float*)d_in[0];
    const float* query   = (const float*)d_in[1];
    const int*   labels  = (const int*)d_in[2];
    // d_in[3] = n_way (assumed 64)
    const float* W       = (const float*)d_in[4];
    const float* bias    = (const float*)d_in[5];
    float* out = (float*)d_out;

    char* ws = (char*)d_ws;
    unsigned short* q_bf     = (unsigned short*)(ws);                 // 67108864 B
    unsigned short* s_bf     = (unsigned short*)(ws + 67108864);      //  8388608 B
    unsigned short* Wt       = (unsigned short*)(ws + 75497472);      //  4194304 B
    unsigned short* q_emb    = (unsigned short*)(ws + 79691776);      // 33554432 B
    float*          proto_sums = (float*)(ws + 113246208);            //   262144 B
    unsigned short* proto_bf = (unsigned short*)(ws + 113508352);     //   131072 B
    float*          qsq      = (float*)(ws + 113639424);              //    65536 B
    float*          psq      = (float*)(ws + 113704960);              //      256 B

    hipMemsetAsync(proto_sums, 0, (size_t)NWAY * DEMB * sizeof(float), stream);
    hipMemsetAsync(qsq, 0, (size_t)NQRY * sizeof(float), stream);

    cvt_f32_bf16<<<2048, 256, 0, stream>>>(query, q_bf, NQRY * DIN);
    cvt_f32_bf16<<<512, 256, 0, stream>>>(support, s_bf, NSUP * DIN);
    dim3 tg(DEMB / 32, DIN / 32);
    cvt_transpose<<<tg, 256, 0, stream>>>(W, Wt);

    gemm_emb<0, 4><<<(NSUP / 128) * (DEMB / 128), 256, 0, stream>>>(
        s_bf, Wt, bias, labels, proto_sums, nullptr, nullptr);
    proto_norm<<<NWAY, 256, 0, stream>>>(proto_sums, labels, proto_bf, psq);
    gemm_emb<1, 8><<<(NQRY / 128) * (DEMB / 256), 256, 0, stream>>>(
        q_bf, Wt, bias, nullptr, nullptr, q_emb, qsq);
    scores_kernel<<<NQRY / 64, 256, 0, stream>>>(q_emb, proto_bf, qsq, psq, out);
}

// Round 17
// 223.447 us; speedup vs baseline: 1.3059x; 1.0545x over previous
//
#include <hip/hip_runtime.h>
#include <hip/hip_bf16.h>
#include <stdint.h>

#define DIN 2048
#define DEMB 1024
#define NSUP 2048
#define NQRY 16384
#define NWAY 64

typedef __attribute__((ext_vector_type(8))) short bf16x8;
typedef __attribute__((ext_vector_type(4))) float f32x4;

__device__ inline unsigned short f2bf(float f) {
    union { float f; uint32_t u; } v; v.f = f;
    uint32_t u = v.u;
    uint32_t r = (u + 0x7FFFu + ((u >> 16) & 1u)) >> 16;
    return (unsigned short)r;
}

#define GLL(g, l) __builtin_amdgcn_global_load_lds(                                   \
    (const __attribute__((address_space(1))) void*)(g),                               \
    (__attribute__((address_space(3))) void*)(l), 16, 0, 0)

// ---------------- conversion kernels ----------------

__global__ void cvt_f32_bf16(const float* __restrict__ in, unsigned short* __restrict__ out, int n) {
    int i = (blockIdx.x * blockDim.x + threadIdx.x) * 4;
    int stride = gridDim.x * blockDim.x * 4;
    for (; i < n; i += stride) {
        float4 v = *(const float4*)(in + i);
        ushort4 o;
        o.x = f2bf(v.x); o.y = f2bf(v.y); o.z = f2bf(v.z); o.w = f2bf(v.w);
        *(ushort4*)(out + i) = o;
    }
}

// W [DIN][DEMB] f32  ->  Wt [DEMB][DIN] bf16
__global__ void cvt_transpose(const float* __restrict__ W, unsigned short* __restrict__ Wt) {
    __shared__ float tile[32][33];
    int c0 = blockIdx.x * 32;
    int r0 = blockIdx.y * 32;
    int tc = threadIdx.x & 31, tr = threadIdx.x >> 5;
    #pragma unroll
    for (int i = 0; i < 4; i++)
        tile[tr + 8*i][tc] = W[(size_t)(r0 + tr + 8*i) * DEMB + c0 + tc];
    __syncthreads();
    #pragma unroll
    for (int i = 0; i < 4; i++)
        Wt[(size_t)(c0 + tr + 8*i) * DIN + r0 + tc] = f2bf(tile[tc][tr + 8*i]);
}

// ================ query GEMM: 256x256 tile, BK=64, 8-wave, 8-PHASE interleave =========
// T3+T4 port (m194-m201 template). 512 thr = 8 waves (2M x 4N), per-wave C = 128x64,
// acc[8][4]. LDS = 2 dbuf x (A 32KB + B 32KB) = 128 KB. Layout [kg 0..7][256][8] elems.
// Half-tiles by k: A-lo = kg0-3, A-hi = kg4-7 (16KB, 2 GLL/thread each); B likewise.
// Iter = 2 K-tiles: T0 (buf0, phases 1-4), T1 (buf1, phases 5-8).
// Phase p: { ds_reads (4 or 8) | stage 1 half-tile | barrier | lgkmcnt(0) | 16 MFMA
//            (setprio) | [vmcnt(4) even phases] barrier }.
// Stage map: ph1..4 -> buf1 {A-lo,B-lo,A-hi,B-hi} of T1 (consumed ph5-8 SAME iter);
//            ph5..8 -> buf0 of next iter's T0.
// RAW: vmcnt(4)+barrier at ph2/4/6/8 confirms the 2 half-tiles read one phase later
//      (issued 3-4 phases earlier); each wave checks its OWN stages pre-barrier, so
//      post-barrier every wave's stages have landed. Never drains to 0 mid-loop.
// WAR: ph1 stage into buf1 issued after prev ph8's closing barrier (all buf1 reads of
//      prev iter retired pre-barrier); ph5 stage into buf0 after ph4's closing barrier.
// Tail: last iter skips ph5-8 stages; ph6 uses vmcnt(0) (ph3/4 stages are the only 4
//      outstanding, vmcnt(4) would not wait).
// Fragment mapping identical to r12's PASSING kernel (absmax 0.25).

#define SG_LO(la, g) { GLL((g), (la)); GLL((g) + 16, (la) + 4096); }
#define SG_HI(la, g) { GLL((g) + 32, (la) + 8192); GLL((g) + 48, (la) + 12288); }

#define READ_B(buf, ks)                                                                \
    _Pragma("unroll") for (int ni = 0; ni < 4; ++ni)                                   \
        bfm[ni] = *(const bf16x8*)&Bs[(buf) * 16384 + (ks) * 8192 + bbase + ni * 128];
#define READ_A(buf, ks, mh)                                                            \
    _Pragma("unroll") for (int mi = 0; mi < 4; ++mi)                                   \
        af[mi] = *(const bf16x8*)&As[(buf) * 16384 + (ks) * 8192 + abase + ((mh)*4 + mi) * 128];
#define MFMA16(mh)                                                                     \
    __builtin_amdgcn_s_setprio(1);                                                     \
    _Pragma("unroll") for (int mi = 0; mi < 4; ++mi)                                   \
        _Pragma("unroll") for (int ni = 0; ni < 4; ++ni)                               \
            acc[(mh)*4 + mi][ni] = __builtin_amdgcn_mfma_f32_16x16x32_bf16(            \
                af[mi], bfm[ni], acc[(mh)*4 + mi][ni], 0, 0, 0);                       \
    __builtin_amdgcn_s_setprio(0);

#define BAR1_LG() do { asm volatile("" ::: "memory"); __builtin_amdgcn_s_barrier();    \
    asm volatile("s_waitcnt lgkmcnt(0)" ::: "memory");                                 \
    __builtin_amdgcn_sched_barrier(0); } while (0)
#define BAR2() do { asm volatile("" ::: "memory"); __builtin_amdgcn_s_barrier();       \
    asm volatile("" ::: "memory"); } while (0)
#define BAR2_VM4() do { asm volatile("s_waitcnt vmcnt(4)" ::: "memory");               \
    __builtin_amdgcn_s_barrier(); asm volatile("" ::: "memory"); } while (0)
#define BAR2_VM0() do { asm volatile("s_waitcnt vmcnt(0)" ::: "memory");               \
    __builtin_amdgcn_s_barrier(); asm volatile("" ::: "memory"); } while (0)

__global__ __launch_bounds__(512) void gemm_query8(
    const unsigned short* __restrict__ A,
    const unsigned short* __restrict__ Bt,
    const float* __restrict__ bias,
    unsigned short* __restrict__ emb_out,
    float* __restrict__ qsq)
{
    __shared__ __attribute__((aligned(16))) unsigned short As[2 * 16384];
    __shared__ __attribute__((aligned(16))) unsigned short Bs[2 * 16384];

    const int tid = threadIdx.x;
    const int nblk = DEMB / 256;          // 4
    // XCD-panel grouping (verified r8). gridDim.x = 256, %8 == 0 -> bijective.
    const int h = blockIdx.x;
    const int cpx = (int)(gridDim.x >> 3);
    const int wg = (h & 7) * cpx + (h >> 3);
    const int bx = wg % nblk, by = wg / nblk;
    const int brow = by * 256, bcol = bx * 256;
    const int lane = tid & 63, wid = tid >> 6;
    const int wr = wid >> 2, wc = wid & 3;          // 2M x 4N

    // staging addresses: thread covers LDS slots tid (kg=tid>>8) and 512+tid (kg+2)
    const int rows = tid & 255, kg0 = tid >> 8;
    const unsigned short* gA = A  + (size_t)(brow + rows) * DIN + kg0 * 8;
    const unsigned short* gB = Bt + (size_t)(bcol + rows) * DIN + kg0 * 8;
    unsigned short* laA0 = As + tid * 8;
    unsigned short* laA1 = As + 16384 + tid * 8;
    unsigned short* laB0 = Bs + tid * 8;
    unsigned short* laB1 = Bs + 16384 + tid * 8;

    // fragment read bases (element units)
    const int kgl = lane >> 4, r = lane & 15;
    const int abase = (kgl * 256 + wr * 128 + r) * 8;
    const int bbase = (kgl * 256 + wc * 64 + r) * 8;

    f32x4 acc[8][4];
    #pragma unroll
    for (int i = 0; i < 8; i++)
        #pragma unroll
        for (int j = 0; j < 4; j++) acc[i][j] = (f32x4)(0.f);

    // prologue: stage T0 (kt=0) into buf0: A-lo, B-lo, A-hi, B-hi (8 loads);
    // vmcnt(4) confirms A-lo+B-lo (oldest 4) for ph1; A-hi/B-hi checked at ph2.
    SG_LO(laA0, gA); SG_LO(laB0, gB);
    SG_HI(laA0, gA); SG_HI(laB0, gB);
    asm volatile("s_waitcnt vmcnt(4)" ::: "memory");
    __builtin_amdgcn_s_barrier();
    asm volatile("" ::: "memory");

    // running stage pointers: buf1 stages kt=2i+1, buf0 stages kt=2i+2
    const unsigned short* gA1 = gA + 64;
    const unsigned short* gB1 = gB + 64;
    const unsigned short* gA0 = gA + 128;
    const unsigned short* gB0 = gB + 128;

    bf16x8 af[4], bfm[4];

#define PH_ITER(LAST)                                                                  \
    /* ph1: T0 ks0 mh0 | stage A-lo(T1)->buf1 */                                       \
    READ_B(0, 0); READ_A(0, 0, 0); SG_LO(laA1, gA1); BAR1_LG(); MFMA16(0); BAR2();     \
    /* ph2: T0 ks0 mh1 | stage B-lo(T1) */                                             \
    READ_A(0, 0, 1); SG_LO(laB1, gB1); BAR1_LG(); MFMA16(1); BAR2_VM4();               \
    /* ph3: T0 ks1 mh0 | stage A-hi(T1) */                                             \
    READ_B(0, 1); READ_A(0, 1, 0); SG_HI(laA1, gA1); BAR1_LG(); MFMA16(0); BAR2();     \
    /* ph4: T0 ks1 mh1 | stage B-hi(T1) */                                             \
    READ_A(0, 1, 1); SG_HI(laB1, gB1); BAR1_LG(); MFMA16(1); BAR2_VM4();               \
    /* ph5: T1 ks0 mh0 | stage A-lo(T0')->buf0 */                                      \
    READ_B(1, 0); READ_A(1, 0, 0);                                                     \
    if (!(LAST)) { SG_LO(laA0, gA0); }                                                 \
    BAR1_LG(); MFMA16(0); BAR2();                                                      \
    /* ph6: T1 ks0 mh1 | stage B-lo(T0') */                                            \
    READ_A(1, 0, 1);                                                                   \
    if (!(LAST)) { SG_LO(laB0, gB0); }                                                 \
    BAR1_LG(); MFMA16(1);                                                              \
    if (LAST) { BAR2_VM0(); } else { BAR2_VM4(); }                                     \
    /* ph7: T1 ks1 mh0 | stage A-hi(T0') */                                            \
    READ_B(1, 1); READ_A(1, 1, 0);                                                     \
    if (!(LAST)) { SG_HI(laA0, gA0); }                                                 \
    BAR1_LG(); MFMA16(0); BAR2();                                                      \
    /* ph8: T1 ks1 mh1 | stage B-hi(T0') */                                            \
    READ_A(1, 1, 1);                                                                   \
    if (!(LAST)) { SG_HI(laB0, gB0); }                                                 \
    BAR1_LG(); MFMA16(1);                                                              \
    if (LAST) { BAR2(); } else { BAR2_VM4(); }

    #pragma unroll 1
    for (int it = 0; it < 15; ++it) {
        PH_ITER(false);
        gA1 += 128; gB1 += 128; gA0 += 128; gB0 += 128;
    }
    PH_ITER(true);
#undef PH_ITER

    // epilogue (identical mapping to r12's verified kernel)
    const int r16 = lane & 15, quad = lane >> 4;
    float bv[4];
    #pragma unroll
    for (int ni = 0; ni < 4; ni++) bv[ni] = bias[bcol + wc * 64 + ni * 16 + r16];

    #pragma unroll
    for (int mi = 0; mi < 8; mi++) {
        float s0 = 0.f, s1 = 0.f, s2 = 0.f, s3 = 0.f;
        #pragma unroll
        for (int j = 0; j < 4; j++) {
            int row = brow + wr * 128 + mi * 16 + quad * 4 + j;
            float sj = 0.f;
            #pragma unroll
            for (int ni = 0; ni < 4; ni++) {
                float e = acc[mi][ni][j] + bv[ni];
                emb_out[(size_t)row * DEMB + bcol + wc * 64 + ni * 16 + r16] = f2bf(e);
                sj += e * e;
            }
            if (j == 0) s0 = sj; else if (j == 1) s1 = sj; else if (j == 2) s2 = sj; else s3 = sj;
        }
        float sv[4] = { s0, s1, s2, s3 };
        #pragma unroll
        for (int j = 0; j < 4; j++) {
            float v = sv[j];
            v += __shfl_xor(v, 1);
            v += __shfl_xor(v, 2);
            v += __shfl_xor(v, 4);
            v += __shfl_xor(v, 8);
            if (r16 == 0) {
                int row = brow + wr * 128 + mi * 16 + quad * 4 + j;
                atomicAdd(&qsq[row], v);
            }
        }
    }
}

// ---------------- support GEMM: r16-verified 3-buf single-barrier BM=128/BN=128 -------
__global__ __launch_bounds__(256, 2) void gemm_support(
    const unsigned short* __restrict__ A,
    const unsigned short* __restrict__ Bt,
    const float* __restrict__ bias,
    const int* __restrict__ labels,
    float* __restrict__ proto_sums)
{
    constexpr int ASZ = 4 * 128 * 8;
    __shared__ __attribute__((aligned(16))) unsigned short AsF[3 * ASZ];
    __shared__ __attribute__((aligned(16))) unsigned short BsF[3 * ASZ];

    const int tid = threadIdx.x;
    const int nblk = DEMB / 128;          // 8
    const int h = blockIdx.x;
    const int cpx = (int)(gridDim.x >> 3);
    const int wg = (h & 7) * cpx + (h >> 3);
    const int bx = wg % nblk, by = wg / nblk;
    const int brow = by * 128, bcol = bx * 128;
    const int lane = tid & 63, wid = tid >> 6;
    const int wr = wid >> 1, wc = wid & 1;

    const int rowa = tid & 127, kga = tid >> 7;
    const unsigned short* ga = A  + (size_t)(brow + rowa) * DIN + kga * 8;
    const unsigned short* gb = Bt + (size_t)(bcol + rowa) * DIN + kga * 8;

    f32x4 acc[4][4];
    #pragma unroll
    for (int i = 0; i < 4; i++)
        #pragma unroll
        for (int j = 0; j < 4; j++) acc[i][j] = (f32x4)(0.f);

    auto stageAB = [&](int buf) {
        unsigned short* la = AsF + buf * ASZ + tid * 8;
        unsigned short* lb = BsF + buf * ASZ + tid * 8;
        GLL(ga, la); GLL(ga + 16, la + 2048);
        GLL(gb, lb); GLL(gb + 16, lb + 2048);
        ga += 32; gb += 32;
    };

    stageAB(0);

    const int kg = lane >> 4, r = lane & 15;
    const int NT = DIN / 32;   // 64
    int cur = 0, nxt = 1;
    for (int t = 0; t < NT; ++t) {
        if (t < NT - 1) {
            stageAB(nxt);
            asm volatile("s_waitcnt vmcnt(4)" ::: "memory");
        } else {
            asm volatile("s_waitcnt vmcnt(0)" ::: "memory");
        }
        __builtin_amdgcn_s_barrier();
        asm volatile("" ::: "memory");

        const unsigned short* Ab = AsF + cur * ASZ;
        const unsigned short* Bb = BsF + cur * ASZ;
        bf16x8 af[4], bfm[4];
        #pragma unroll
        for (int mi = 0; mi < 4; mi++)
            af[mi] = *(const bf16x8*)&Ab[(kg * 128 + wr * 64 + mi * 16 + r) * 8];
        #pragma unroll
        for (int ni = 0; ni < 4; ni++)
            bfm[ni] = *(const bf16x8*)&Bb[(kg * 128 + wc * 64 + ni * 16 + r) * 8];
        __builtin_amdgcn_s_setprio(1);
        #pragma unroll
        for (int mi = 0; mi < 4; mi++)
            #pragma unroll
            for (int ni = 0; ni < 4; ni++)
                acc[mi][ni] = __builtin_amdgcn_mfma_f32_16x16x32_bf16(af[mi], bfm[ni], acc[mi][ni], 0, 0, 0);
        __builtin_amdgcn_s_setprio(0);
        asm volatile("" ::: "memory");

        cur = (cur == 2) ? 0 : cur + 1;
        nxt = (nxt == 2) ? 0 : nxt + 1;
    }

    const int r16 = lane & 15, quad = lane >> 4;
    float bv[4];
    #pragma unroll
    for (int ni = 0; ni < 4; ni++) bv[ni] = bias[bcol + wc * 64 + ni * 16 + r16];

    #pragma unroll
    for (int mi = 0; mi < 4; mi++) {
        #pragma unroll
        for (int j = 0; j < 4; j++) {
            int row = brow + wr * 64 + mi * 16 + quad * 4 + j;
            int lab = labels[row];
            #pragma unroll
            for (int ni = 0; ni < 4; ni++) {
                float e = acc[mi][ni][j] + bv[ni];
                atomicAdd(&proto_sums[(size_t)lab * DEMB + bcol + wc * 64 + ni * 16 + r16], e);
            }
        }
    }
}

// ---------------- prototype normalize ----------------
__global__ void proto_norm(const float* __restrict__ proto_sums,
                           const int* __restrict__ labels,
                           unsigned short* __restrict__ proto_bf16,
                           float* __restrict__ psq) {
    int c = blockIdx.x;
    int tid = threadIdx.x;
    int cnt = 0;
    for (int i = tid; i < NSUP; i += 256) cnt += (labels[i] == c) ? 1 : 0;
    #pragma unroll
    for (int m = 1; m < 64; m <<= 1) cnt += __shfl_xor(cnt, m);
    __shared__ int warp_cnt[4];
    __shared__ float warp_ss[4];
    if ((tid & 63) == 0) warp_cnt[tid >> 6] = cnt;
    __syncthreads();
    int total = warp_cnt[0] + warp_cnt[1] + warp_cnt[2] + warp_cnt[3];
    float inv = 1.0f / (float)total;
    float ss = 0.f;
    for (int j = tid; j < DEMB; j += 256) {
        float p = proto_sums[(size_t)c * DEMB + j] * inv;
        proto_bf16[(size_t)c * DEMB + j] = f2bf(p);
        ss += p * p;
    }
    #pragma unroll
    for (int m = 1; m < 64; m <<= 1) ss += __shfl_xor(ss, m);
    if ((tid & 63) == 0) warp_ss[tid >> 6] = ss;
    __syncthreads();
    if (tid == 0) psq[c] = warp_ss[0] + warp_ss[1] + warp_ss[2] + warp_ss[3];
}

// ---------------- scores: out[q][c] = -sqrt(max(qsq+psq-2*dot,0)) ----------------
__global__ __launch_bounds__(256) void scores_kernel(
    const unsigned short* __restrict__ q_emb,
    const unsigned short* __restrict__ protos,
    const float* __restrict__ qsq, const float* __restrict__ psq,
    float* __restrict__ out)
{
    int tid = threadIdx.x, lane = tid & 63, wid = tid >> 6;
    int q0 = blockIdx.x * 64 + wid * 16;
    int r = lane & 15, quad = lane >> 4;
    f32x4 acc[4];
    #pragma unroll
    for (int i = 0; i < 4; i++) acc[i] = (f32x4)(0.f);
    const unsigned short* arow = q_emb + (size_t)(q0 + r) * DEMB + quad * 8;
    for (int k0 = 0; k0 < DEMB; k0 += 32) {
        bf16x8 a = *(const bf16x8*)(arow + k0);
        #pragma unroll
        for (int ni = 0; ni < 4; ni++) {
            bf16x8 bfrag = *(const bf16x8*)(protos + (size_t)(ni * 16 + r) * DEMB + k0 + quad * 8);
            acc[ni] = __builtin_amdgcn_mfma_f32_16x16x32_bf16(a, bfrag, acc[ni], 0, 0, 0);
        }
    }
    #pragma unroll
    for (int ni = 0; ni < 4; ni++) {
        int c = ni * 16 + r;
        float ps = psq[c];
        #pragma unroll
        for (int j = 0; j < 4; j++) {
            int row = q0 + quad * 4 + j;
            float d2 = qsq[row] + ps - 2.0f * acc[ni][j];
            d2 = fmaxf(d2, 0.0f);
            out[(size_t)row * NWAY + c] = -sqrtf(d2);
        }
    }
}

// ---------------- launch ----------------
extern "C" void kernel_launch(void* const* d_in, const int* in_sizes, int n_in,
                              void* d_out, int out_size, void* d_ws, size_t ws_size,
                              hipStream_t stream) {
    const float* support = (const float*)d_in[0];
    const float* query   = (const float*)d_in[1];
    const int*   labels  = (const int*)d_in[2];
    // d_in[3] = n_way (assumed 64)
    const float* W       = (const float*)d_in[4];
    const float* bias    = (const float*)d_in[5];
    float* out = (float*)d_out;

    char* ws = (char*)d_ws;
    unsigned short* q_bf     = (unsigned short*)(ws);                 // 67108864 B
    unsigned short* s_bf     = (unsigned short*)(ws + 67108864);      //  8388608 B
    unsigned short* Wt       = (unsigned short*)(ws + 75497472);      //  4194304 B
    unsigned short* q_emb    = (unsigned short*)(ws + 79691776);      // 33554432 B
    float*          proto_sums = (float*)(ws + 113246208);            //   262144 B
    unsigned short* proto_bf = (unsigned short*)(ws + 113508352);     //   131072 B
    float*          qsq      = (float*)(ws + 113639424);              //    65536 B
    float*          psq      = (float*)(ws + 113704960);              //      256 B

    hipMemsetAsync(proto_sums, 0, (size_t)NWAY * DEMB * sizeof(float), stream);
    hipMemsetAsync(qsq, 0, (size_t)NQRY * sizeof(float), stream);

    cvt_f32_bf16<<<2048, 256, 0, stream>>>(query, q_bf, NQRY * DIN);
    cvt_f32_bf16<<<512, 256, 0, stream>>>(support, s_bf, NSUP * DIN);
    dim3 tg(DEMB / 32, DIN / 32);
    cvt_transpose<<<tg, 256, 0, stream>>>(W, Wt);

    gemm_support<<<(NSUP / 128) * (DEMB / 128), 256, 0, stream>>>(
        s_bf, Wt, bias, labels, proto_sums);
    proto_norm<<<NWAY, 256, 0, stream>>>(proto_sums, labels, proto_bf, psq);
    gemm_query8<<<(NQRY / 256) * (DEMB / 256), 512, 0, stream>>>(
        q_bf, Wt, bias, q_emb, qsq);
    scores_kernel<<<NQRY / 64, 256, 0, stream>>>(q_emb, proto_bf, qsq, psq, out);
}

// Round 18
// 212.950 us; speedup vs baseline: 1.3703x; 1.0493x over previous
//
#include <hip/hip_runtime.h>
#include <hip/hip_bf16.h>
#include <stdint.h>

#define DIN 2048
#define DEMB 1024
#define NSUP 2048
#define NQRY 16384
#define NWAY 64

typedef __attribute__((ext_vector_type(8))) short bf16x8;
typedef __attribute__((ext_vector_type(4))) float f32x4;

__device__ inline unsigned short f2bf(float f) {
    union { float f; uint32_t u; } v; v.f = f;
    uint32_t u = v.u;
    uint32_t r = (u + 0x7FFFu + ((u >> 16) & 1u)) >> 16;
    return (unsigned short)r;
}

#define GLL(g, l) __builtin_amdgcn_global_load_lds(                                   \
    (const __attribute__((address_space(1))) void*)(g),                               \
    (__attribute__((address_space(3))) void*)(l), 16, 0, 0)

// ================ prep: query cvt | support cvt | W transpose | zero accumulators ====
// One kernel, block ranges. Replaces 3 kernels + 2 memsets (graph 10 -> 5 nodes);
// the small ops ride along the 201MB query convert's BW window.
__global__ __launch_bounds__(256) void prep_kernel(
    const float* __restrict__ query, const float* __restrict__ support,
    const float* __restrict__ W,
    unsigned short* __restrict__ q_bf, unsigned short* __restrict__ s_bf,
    unsigned short* __restrict__ Wt,
    float* __restrict__ proto_sums, float* __restrict__ qsq)
{
    __shared__ float tile[32][33];
    const int b = blockIdx.x;
    if (b < 2048) {                       // query f32 -> bf16 (33.5M elems)
        int i = (b * 256 + threadIdx.x) * 4;
        const int stride = 2048 * 256 * 4;
        for (; i < NQRY * DIN; i += stride) {
            float4 v = *(const float4*)(query + i);
            ushort4 o;
            o.x = f2bf(v.x); o.y = f2bf(v.y); o.z = f2bf(v.z); o.w = f2bf(v.w);
            *(ushort4*)(q_bf + i) = o;
        }
    } else if (b < 2560) {                // support f32 -> bf16 (4.2M elems)
        int i = ((b - 2048) * 256 + threadIdx.x) * 4;
        const int stride = 512 * 256 * 4;
        for (; i < NSUP * DIN; i += stride) {
            float4 v = *(const float4*)(support + i);
            ushort4 o;
            o.x = f2bf(v.x); o.y = f2bf(v.y); o.z = f2bf(v.z); o.w = f2bf(v.w);
            *(ushort4*)(s_bf + i) = o;
        }
    } else if (b < 4608) {                // W [DIN][DEMB] f32 -> Wt [DEMB][DIN] bf16
        const int bb = b - 2560;
        const int c0 = (bb & 31) * 32, r0 = (bb >> 5) * 32;
        const int tc = threadIdx.x & 31, tr = threadIdx.x >> 5;
        #pragma unroll
        for (int i = 0; i < 4; i++)
            tile[tr + 8*i][tc] = W[(size_t)(r0 + tr + 8*i) * DEMB + c0 + tc];
        __syncthreads();
        #pragma unroll
        for (int i = 0; i < 4; i++)
            Wt[(size_t)(c0 + tr + 8*i) * DIN + r0 + tc] = f2bf(tile[tc][tr + 8*i]);
    } else {                              // zero proto_sums (65536 f) + qsq (16384 f)
        const int off = ((b - 4608) * 256 + threadIdx.x) * 4;
        float4 z = { 0.f, 0.f, 0.f, 0.f };
        if (off < NWAY * DEMB) *(float4*)(proto_sums + off) = z;
        else                   *(float4*)(qsq + off - NWAY * DEMB) = z;
    }
}

// ================ query GEMM: 256x256, BK=64, 8-wave, 8-PHASE (r17, UNCHANGED) =======
// Verified r17: 108us, MfmaUtil 25.4%, absmax 0.25. See r17 for full race audit.

#define SG_LO(la, g) { GLL((g), (la)); GLL((g) + 16, (la) + 4096); }
#define SG_HI(la, g) { GLL((g) + 32, (la) + 8192); GLL((g) + 48, (la) + 12288); }

#define READ_B(buf, ks)                                                                \
    _Pragma("unroll") for (int ni = 0; ni < 4; ++ni)                                   \
        bfm[ni] = *(const bf16x8*)&Bs[(buf) * 16384 + (ks) * 8192 + bbase + ni * 128];
#define READ_A(buf, ks, mh)                                                            \
    _Pragma("unroll") for (int mi = 0; mi < 4; ++mi)                                   \
        af[mi] = *(const bf16x8*)&As[(buf) * 16384 + (ks) * 8192 + abase + ((mh)*4 + mi) * 128];
#define MFMA16(mh)                                                                     \
    __builtin_amdgcn_s_setprio(1);                                                     \
    _Pragma("unroll") for (int mi = 0; mi < 4; ++mi)                                   \
        _Pragma("unroll") for (int ni = 0; ni < 4; ++ni)                               \
            acc[(mh)*4 + mi][ni] = __builtin_amdgcn_mfma_f32_16x16x32_bf16(            \
                af[mi], bfm[ni], acc[(mh)*4 + mi][ni], 0, 0, 0);                       \
    __builtin_amdgcn_s_setprio(0);

#define BAR1_LG() do { asm volatile("" ::: "memory"); __builtin_amdgcn_s_barrier();    \
    asm volatile("s_waitcnt lgkmcnt(0)" ::: "memory");                                 \
    __builtin_amdgcn_sched_barrier(0); } while (0)
#define BAR2() do { asm volatile("" ::: "memory"); __builtin_amdgcn_s_barrier();       \
    asm volatile("" ::: "memory"); } while (0)
#define BAR2_VM4() do { asm volatile("s_waitcnt vmcnt(4)" ::: "memory");               \
    __builtin_amdgcn_s_barrier(); asm volatile("" ::: "memory"); } while (0)
#define BAR2_VM0() do { asm volatile("s_waitcnt vmcnt(0)" ::: "memory");               \
    __builtin_amdgcn_s_barrier(); asm volatile("" ::: "memory"); } while (0)

__global__ __launch_bounds__(512) void gemm_query8(
    const unsigned short* __restrict__ A,
    const unsigned short* __restrict__ Bt,
    const float* __restrict__ bias,
    unsigned short* __restrict__ emb_out,
    float* __restrict__ qsq)
{
    __shared__ __attribute__((aligned(16))) unsigned short As[2 * 16384];
    __shared__ __attribute__((aligned(16))) unsigned short Bs[2 * 16384];

    const int tid = threadIdx.x;
    const int nblk = DEMB / 256;          // 4
    const int h = blockIdx.x;
    const int cpx = (int)(gridDim.x >> 3);
    const int wg = (h & 7) * cpx + (h >> 3);
    const int bx = wg % nblk, by = wg / nblk;
    const int brow = by * 256, bcol = bx * 256;
    const int lane = tid & 63, wid = tid >> 6;
    const int wr = wid >> 2, wc = wid & 3;

    const int rows = tid & 255, kg0 = tid >> 8;
    const unsigned short* gA = A  + (size_t)(brow + rows) * DIN + kg0 * 8;
    const unsigned short* gB = Bt + (size_t)(bcol + rows) * DIN + kg0 * 8;
    unsigned short* laA0 = As + tid * 8;
    unsigned short* laA1 = As + 16384 + tid * 8;
    unsigned short* laB0 = Bs + tid * 8;
    unsigned short* laB1 = Bs + 16384 + tid * 8;

    const int kgl = lane >> 4, r = lane & 15;
    const int abase = (kgl * 256 + wr * 128 + r) * 8;
    const int bbase = (kgl * 256 + wc * 64 + r) * 8;

    f32x4 acc[8][4];
    #pragma unroll
    for (int i = 0; i < 8; i++)
        #pragma unroll
        for (int j = 0; j < 4; j++) acc[i][j] = (f32x4)(0.f);

    SG_LO(laA0, gA); SG_LO(laB0, gB);
    SG_HI(laA0, gA); SG_HI(laB0, gB);
    asm volatile("s_waitcnt vmcnt(4)" ::: "memory");
    __builtin_amdgcn_s_barrier();
    asm volatile("" ::: "memory");

    const unsigned short* gA1 = gA + 64;
    const unsigned short* gB1 = gB + 64;
    const unsigned short* gA0 = gA + 128;
    const unsigned short* gB0 = gB + 128;

    bf16x8 af[4], bfm[4];

#define PH_ITER(LAST)                                                                  \
    READ_B(0, 0); READ_A(0, 0, 0); SG_LO(laA1, gA1); BAR1_LG(); MFMA16(0); BAR2();     \
    READ_A(0, 0, 1); SG_LO(laB1, gB1); BAR1_LG(); MFMA16(1); BAR2_VM4();               \
    READ_B(0, 1); READ_A(0, 1, 0); SG_HI(laA1, gA1); BAR1_LG(); MFMA16(0); BAR2();     \
    READ_A(0, 1, 1); SG_HI(laB1, gB1); BAR1_LG(); MFMA16(1); BAR2_VM4();               \
    READ_B(1, 0); READ_A(1, 0, 0);                                                     \
    if (!(LAST)) { SG_LO(laA0, gA0); }                                                 \
    BAR1_LG(); MFMA16(0); BAR2();                                                      \
    READ_A(1, 0, 1);                                                                   \
    if (!(LAST)) { SG_LO(laB0, gB0); }                                                 \
    BAR1_LG(); MFMA16(1);                                                              \
    if (LAST) { BAR2_VM0(); } else { BAR2_VM4(); }                                     \
    READ_B(1, 1); READ_A(1, 1, 0);                                                     \
    if (!(LAST)) { SG_HI(laA0, gA0); }                                                 \
    BAR1_LG(); MFMA16(0); BAR2();                                                      \
    READ_A(1, 1, 1);                                                                   \
    if (!(LAST)) { SG_HI(laB0, gB0); }                                                 \
    BAR1_LG(); MFMA16(1);                                                              \
    if (LAST) { BAR2(); } else { BAR2_VM4(); }

    #pragma unroll 1
    for (int it = 0; it < 15; ++it) {
        PH_ITER(false);
        gA1 += 128; gB1 += 128; gA0 += 128; gB0 += 128;
    }
    PH_ITER(true);
#undef PH_ITER

    const int r16 = lane & 15, quad = lane >> 4;
    float bv[4];
    #pragma unroll
    for (int ni = 0; ni < 4; ni++) bv[ni] = bias[bcol + wc * 64 + ni * 16 + r16];

    #pragma unroll
    for (int mi = 0; mi < 8; mi++) {
        float s0 = 0.f, s1 = 0.f, s2 = 0.f, s3 = 0.f;
        #pragma unroll
        for (int j = 0; j < 4; j++) {
            int row = brow + wr * 128 + mi * 16 + quad * 4 + j;
            float sj = 0.f;
            #pragma unroll
            for (int ni = 0; ni < 4; ni++) {
                float e = acc[mi][ni][j] + bv[ni];
                emb_out[(size_t)row * DEMB + bcol + wc * 64 + ni * 16 + r16] = f2bf(e);
                sj += e * e;
            }
            if (j == 0) s0 = sj; else if (j == 1) s1 = sj; else if (j == 2) s2 = sj; else s3 = sj;
        }
        float sv[4] = { s0, s1, s2, s3 };
        #pragma unroll
        for (int j = 0; j < 4; j++) {
            float v = sv[j];
            v += __shfl_xor(v, 1);
            v += __shfl_xor(v, 2);
            v += __shfl_xor(v, 4);
            v += __shfl_xor(v, 8);
            if (r16 == 0) {
                int row = brow + wr * 128 + mi * 16 + quad * 4 + j;
                atomicAdd(&qsq[row], v);
            }
        }
    }
}

// ---------------- support GEMM: BM=64, BN=128, 3-buf single-barrier (r16 discipline) --
// grid = (2048/64)*(1024/128) = 256 blocks = 1/CU (was 128 = half idle).
// 4 waves, per-wave output 64x32, acc[4][2]. Stage = 3 GLL/thread; steady vmcnt(3).
__global__ __launch_bounds__(256, 2) void gemm_support(
    const unsigned short* __restrict__ A,
    const unsigned short* __restrict__ Bt,
    const float* __restrict__ bias,
    const int* __restrict__ labels,
    float* __restrict__ proto_sums)
{
    constexpr int ASZ = 4 * 64 * 8;       // 2048 elems / buf
    constexpr int BSZ = 4 * 128 * 8;      // 4096 elems / buf
    __shared__ __attribute__((aligned(16))) unsigned short AsF[3 * ASZ];
    __shared__ __attribute__((aligned(16))) unsigned short BsF[3 * BSZ];

    const int tid = threadIdx.x;
    const int nblk = DEMB / 128;          // 8
    const int h = blockIdx.x;
    const int cpx = (int)(gridDim.x >> 3);
    const int wg = (h & 7) * cpx + (h >> 3);
    const int bx = wg % nblk, by = wg / nblk;
    const int brow = by * 64, bcol = bx * 128;
    const int lane = tid & 63, wid = tid >> 6;
    const int wc = wid;                   // 1M x 4N

    const unsigned short* ga = A  + (size_t)(brow + (tid & 63)) * DIN + (tid >> 6) * 8;
    const unsigned short* gb = Bt + (size_t)(bcol + (tid & 127)) * DIN + (tid >> 7) * 8;

    f32x4 acc[4][2];
    #pragma unroll
    for (int i = 0; i < 4; i++)
        #pragma unroll
        for (int j = 0; j < 2; j++) acc[i][j] = (f32x4)(0.f);

    auto stageAB = [&](int buf) {
        unsigned short* la = AsF + buf * ASZ + tid * 8;
        unsigned short* lb = BsF + buf * BSZ + tid * 8;
        GLL(ga, la);
        GLL(gb, lb); GLL(gb + 16, lb + 2048);
        ga += 32; gb += 32;
    };

    stageAB(0);

    const int kg = lane >> 4, r = lane & 15;
    const int NT = DIN / 32;   // 64
    int cur = 0, nxt = 1;
    for (int t = 0; t < NT; ++t) {
        if (t < NT - 1) {
            stageAB(nxt);
            asm volatile("s_waitcnt vmcnt(3)" ::: "memory");
        } else {
            asm volatile("s_waitcnt vmcnt(0)" ::: "memory");
        }
        __builtin_amdgcn_s_barrier();
        asm volatile("" ::: "memory");

        const unsigned short* Ab = AsF + cur * ASZ;
        const unsigned short* Bb = BsF + cur * BSZ;
        bf16x8 af[4], bfm[2];
        #pragma unroll
        for (int mi = 0; mi < 4; mi++)
            af[mi] = *(const bf16x8*)&Ab[(kg * 64 + mi * 16 + r) * 8];
        #pragma unroll
        for (int ni = 0; ni < 2; ni++)
            bfm[ni] = *(const bf16x8*)&Bb[(kg * 128 + wc * 32 + ni * 16 + r) * 8];
        __builtin_amdgcn_s_setprio(1);
        #pragma unroll
        for (int mi = 0; mi < 4; mi++)
            #pragma unroll
            for (int ni = 0; ni < 2; ni++)
                acc[mi][ni] = __builtin_amdgcn_mfma_f32_16x16x32_bf16(af[mi], bfm[ni], acc[mi][ni], 0, 0, 0);
        __builtin_amdgcn_s_setprio(0);
        asm volatile("" ::: "memory");

        cur = (cur == 2) ? 0 : cur + 1;
        nxt = (nxt == 2) ? 0 : nxt + 1;
    }

    const int r16 = lane & 15, quad = lane >> 4;
    float bv[2];
    #pragma unroll
    for (int ni = 0; ni < 2; ni++) bv[ni] = bias[bcol + wc * 32 + ni * 16 + r16];

    #pragma unroll
    for (int mi = 0; mi < 4; mi++) {
        #pragma unroll
        for (int j = 0; j < 4; j++) {
            int row = brow + mi * 16 + quad * 4 + j;
            int lab = labels[row];
            #pragma unroll
            for (int ni = 0; ni < 2; ni++) {
                float e = acc[mi][ni][j] + bv[ni];
                atomicAdd(&proto_sums[(size_t)lab * DEMB + bcol + wc * 32 + ni * 16 + r16], e);
            }
        }
    }
}

// ---------------- prototype normalize ----------------
__global__ void proto_norm(const float* __restrict__ proto_sums,
                           const int* __restrict__ labels,
                           unsigned short* __restrict__ proto_bf16,
                           float* __restrict__ psq) {
    int c = blockIdx.x;
    int tid = threadIdx.x;
    int cnt = 0;
    for (int i = tid; i < NSUP; i += 256) cnt += (labels[i] == c) ? 1 : 0;
    #pragma unroll
    for (int m = 1; m < 64; m <<= 1) cnt += __shfl_xor(cnt, m);
    __shared__ int warp_cnt[4];
    __shared__ float warp_ss[4];
    if ((tid & 63) == 0) warp_cnt[tid >> 6] = cnt;
    __syncthreads();
    int total = warp_cnt[0] + warp_cnt[1] + warp_cnt[2] + warp_cnt[3];
    float inv = 1.0f / (float)total;
    float ss = 0.f;
    for (int j = tid; j < DEMB; j += 256) {
        float p = proto_sums[(size_t)c * DEMB + j] * inv;
        proto_bf16[(size_t)c * DEMB + j] = f2bf(p);
        ss += p * p;
    }
    #pragma unroll
    for (int m = 1; m < 64; m <<= 1) ss += __shfl_xor(ss, m);
    if ((tid & 63) == 0) warp_ss[tid >> 6] = ss;
    __syncthreads();
    if (tid == 0) psq[c] = warp_ss[0] + warp_ss[1] + warp_ss[2] + warp_ss[3];
}

// ---------------- scores: out[q][c] = -sqrt(max(qsq+psq-2*dot,0)) ----------------
__global__ __launch_bounds__(256) void scores_kernel(
    const unsigned short* __restrict__ q_emb,
    const unsigned short* __restrict__ protos,
    const float* __restrict__ qsq, const float* __restrict__ psq,
    float* __restrict__ out)
{
    int tid = threadIdx.x, lane = tid & 63, wid = tid >> 6;
    int q0 = blockIdx.x * 64 + wid * 16;
    int r = lane & 15, quad = lane >> 4;
    f32x4 acc[4];
    #pragma unroll
    for (int i = 0; i < 4; i++) acc[i] = (f32x4)(0.f);
    const unsigned short* arow = q_emb + (size_t)(q0 + r) * DEMB + quad * 8;
    for (int k0 = 0; k0 < DEMB; k0 += 32) {
        bf16x8 a = *(const bf16x8*)(arow + k0);
        #pragma unroll
        for (int ni = 0; ni < 4; ni++) {
            bf16x8 bfrag = *(const bf16x8*)(protos + (size_t)(ni * 16 + r) * DEMB + k0 + quad * 8);
            acc[ni] = __builtin_amdgcn_mfma_f32_16x16x32_bf16(a, bfrag, acc[ni], 0, 0, 0);
        }
    }
    #pragma unroll
    for (int ni = 0; ni < 4; ni++) {
        int c = ni * 16 + r;
        float ps = psq[c];
        #pragma unroll
        for (int j = 0; j < 4; j++) {
            int row = q0 + quad * 4 + j;
            float d2 = qsq[row] + ps - 2.0f * acc[ni][j];
            d2 = fmaxf(d2, 0.0f);
            out[(size_t)row * NWAY + c] = -sqrtf(d2);
        }
    }
}

// ---------------- launch ----------------
extern "C" void kernel_launch(void* const* d_in, const int* in_sizes, int n_in,
                              void* d_out, int out_size, void* d_ws, size_t ws_size,
                              hipStream_t stream) {
    const float* support = (const float*)d_in[0];
    const float* query   = (const float*)d_in[1];
    const int*   labels  = (const int*)d_in[2];
    // d_in[3] = n_way (assumed 64)
    const float* W       = (const float*)d_in[4];
    const float* bias    = (const float*)d_in[5];
    float* out = (float*)d_out;

    char* ws = (char*)d_ws;
    unsigned short* q_bf     = (unsigned short*)(ws);                 // 67108864 B
    unsigned short* s_bf     = (unsigned short*)(ws + 67108864);      //  8388608 B
    unsigned short* Wt       = (unsigned short*)(ws + 75497472);      //  4194304 B
    unsigned short* q_emb    = (unsigned short*)(ws + 79691776);      // 33554432 B
    float*          proto_sums = (float*)(ws + 113246208);            //   262144 B
    unsigned short* proto_bf = (unsigned short*)(ws + 113508352);     //   131072 B
    float*          qsq      = (float*)(ws + 113639424);              //    65536 B
    float*          psq      = (float*)(ws + 113704960);              //      256 B

    // prep: [0,2048) query cvt | [2048,2560) support cvt | [2560,4608) W transpose
    //       | [4608,4688) zero proto_sums+qsq
    prep_kernel<<<4688, 256, 0, stream>>>(query, support, W, q_bf, s_bf, Wt,
                                          proto_sums, qsq);
    gemm_support<<<(NSUP / 64) * (DEMB / 128), 256, 0, stream>>>(
        s_bf, Wt, bias, labels, proto_sums);
    proto_norm<<<NWAY, 256, 0, stream>>>(proto_sums, labels, proto_bf, psq);
    gemm_query8<<<(NQRY / 256) * (DEMB / 256), 512, 0, stream>>>(
        q_bf, Wt, bias, q_emb, qsq);
    scores_kernel<<<NQRY / 64, 256, 0, stream>>>(q_emb, proto_bf, qsq, psq, out);
}